// Round 12
// baseline (170.240 us; speedup 1.0000x reference)
//
#include <hip/hip_runtime.h>
#include <hip/hip_fp16.h>
#include <math.h>

#define N_NODES  50000
#define N_EDGES  800000
#define IN_DIM   64
#define HID_DIM  64
#define N_CLS    10
#define NBUCK    196      // ceil(N_NODES/256) coarse buckets (dst >> 8)
#define PBLK     64       // partition blocks
#define PCHUNK   (N_EDGES / PBLK)   // 12500 edges per partition block (exact)
#define SCANTOT  (NBUCK * PBLK)     // 12544
#define FCAP     8192     // k_fine LDS edge cache capacity (32 KB)

// unpack 4 fp16 (carried in a float2) to float4
__device__ __forceinline__ float4 h4_to_f4(float2 raw) {
    union { float2 f; __half2 h[2]; } u;
    u.f = raw;
    float2 lo = __half22float2(u.h[0]);
    float2 hi = __half22float2(u.h[1]);
    return make_float4(lo.x, lo.y, hi.x, hi.y);
}
// pack float4 -> 4 fp16 in a float2
__device__ __forceinline__ float2 f4_to_h4(float4 v) {
    union { float2 f; __half2 h[2]; } u;
    u.h[0] = __floats2half2_rn(v.x, v.y);
    u.h[1] = __floats2half2_rn(v.z, v.w);
    return u.f;
}

// ---------------- pass 1a: per-block coarse histogram (dst>>8) ----------------
__global__ __launch_bounds__(1024) void k_chist(const int* __restrict__ dst,
                                                int* __restrict__ bhist) {
    __shared__ int lh[NBUCK];
    int t = threadIdx.x;
    for (int i = t; i < NBUCK; i += 1024) lh[i] = 0;
    __syncthreads();
    int beg = blockIdx.x * PCHUNK, end = beg + PCHUNK;
    for (int e = beg + t; e < end; e += 1024)
        atomicAdd(&lh[dst[e] >> 8], 1);          // LDS atomic
    __syncthreads();
    for (int i = t; i < NBUCK; i += 1024)
        bhist[i * PBLK + blockIdx.x] = lh[i];    // bin-major
}

// ---------------- pass 1b: scan 12544 (bin,block) counts in LDS ----------------
__global__ __launch_bounds__(1024) void k_cscan(int* __restrict__ bhist,
                                                int* __restrict__ bbase,
                                                int* __restrict__ off) {
    __shared__ int s[SCANTOT];
    __shared__ int tsum[1024];
    int t = threadIdx.x;
    for (int i = t; i < SCANTOT; i += 1024) s[i] = bhist[i];   // coalesced
    __syncthreads();
    const int IT = (SCANTOT + 1023) / 1024;  // 13
    int base_i = t * IT;
    int sum = 0;
    for (int j = 0; j < IT; ++j) {
        int i = base_i + j;
        if (i < SCANTOT) sum += s[i];
    }
    tsum[t] = sum;
    __syncthreads();
    for (int d = 1; d < 1024; d <<= 1) {
        int v = (t >= d) ? tsum[t - d] : 0;
        __syncthreads();
        if (t >= d) tsum[t] += v;
        __syncthreads();
    }
    int run = (t > 0) ? tsum[t - 1] : 0;
    for (int j = 0; j < IT; ++j) {
        int i = base_i + j;
        if (i < SCANTOT) { int c = s[i]; s[i] = run; run += c; }
    }
    __syncthreads();
    for (int i = t; i < SCANTOT; i += 1024) bhist[i] = s[i];
    for (int i = t; i < NBUCK; i += 1024) bbase[i] = s[i * PBLK];
    if (t == 0) { bbase[NBUCK] = N_EDGES; off[N_NODES] = N_EDGES; }
}

// ---------------- pass 1c: partition edges into coarse buckets (packed) ----------------
__global__ __launch_bounds__(1024) void k_partition(const int* __restrict__ src,
                                                    const int* __restrict__ dst,
                                                    const int* __restrict__ bhist,
                                                    int* __restrict__ packed) {
    __shared__ int cur[NBUCK];
    int t = threadIdx.x;
    for (int i = t; i < NBUCK; i += 1024)
        cur[i] = bhist[i * PBLK + blockIdx.x];
    __syncthreads();
    int beg = blockIdx.x * PCHUNK, end = beg + PCHUNK;
    for (int e = beg + t; e < end; e += 1024) {
        int d = dst[e], sv = src[e];
        int slot = atomicAdd(&cur[d >> 8], 1);          // LDS atomic
        packed[slot] = ((d & 255) << 16) | sv;          // run-contiguous per (blk,bin)
    }
}

// ---------------- pass 2: per-bucket fine CSR (ushort) + off + dinv ----------------
__global__ __launch_bounds__(1024) void k_fine(const int* __restrict__ packed,
                                               const int* __restrict__ bbase,
                                               int* __restrict__ off,
                                               float* __restrict__ dinv,
                                               unsigned short* __restrict__ csr_src) {
    __shared__ int hist[256];
    __shared__ int scan[256];
    __shared__ int cur[256];
    __shared__ int ecache[FCAP];            // 32 KB
    int t = threadIdx.x;
    int bucket = blockIdx.x;
    if (t < 256) hist[t] = 0;
    __syncthreads();
    int beg = bbase[bucket], end = bbase[bucket + 1];
    int ne = end - beg;
    bool cached = ne <= FCAP;
    if (cached) {
        for (int i = t; i < ne; i += 1024) {
            int p = packed[beg + i];
            ecache[i] = p;
            atomicAdd(&hist[p >> 16], 1);
        }
    } else {
        for (int i = beg + t; i < end; i += 1024)
            atomicAdd(&hist[packed[i] >> 16], 1);
    }
    __syncthreads();
    if (t < 256) scan[t] = hist[t];
    __syncthreads();
    for (int d = 1; d < 256; d <<= 1) {
        int v = 0;
        if (t < 256 && t >= d) v = scan[t - d];
        __syncthreads();
        if (t < 256 && t >= d) scan[t] += v;
        __syncthreads();
    }
    if (t < 256) {
        int excl = beg + scan[t] - hist[t];
        cur[t] = excl;
        int node = bucket * 256 + t;
        if (node < N_NODES) {
            off[node] = excl;
            dinv[node] = rsqrtf((float)(hist[t] + 1));   // +1 self-loop
        }
    }
    __syncthreads();
    if (cached) {
        for (int i = t; i < ne; i += 1024) {
            int p = ecache[i];
            int slot = atomicAdd(&cur[p >> 16], 1);      // LDS atomic
            csr_src[slot] = (unsigned short)(p & 0xFFFF);
        }
    } else {
        for (int i = beg + t; i < end; i += 1024) {
            int p = packed[i];
            int slot = atomicAdd(&cur[p >> 16], 1);
            csr_src[slot] = (unsigned short)(p & 0xFFFF);
        }
    }
}

// ---------------- xl' = fp16((x @ W1) * dinv[row]) — 64-row tile, 4 rows/thread ----------------
__global__ __launch_bounds__(256) void k_xw64(const float* __restrict__ x,
                                              const float* __restrict__ W,
                                              const float* __restrict__ dinv,
                                              float2* __restrict__ out /* fp16x4 */) {
    __shared__ float4 sW4[IN_DIM * 16];   // W1: 64 rows x 16 col-quads (16 KB)
    __shared__ float4 sx4[64 * 16];       // x tile: 64 rows x 16 k-quads (16 KB)
    int tid = threadIdx.x;
    const float4* W4 = (const float4*)W;
#pragma unroll
    for (int i = 0; i < 4; ++i) sW4[tid + 256 * i] = W4[tid + 256 * i];
    int rowbase = blockIdx.x * 64;
    const float4* xb = (const float4*)(x + (size_t)rowbase * IN_DIM);
    int maxq = (N_NODES - rowbase) * 16;           // valid float4 count in tile
#pragma unroll
    for (int i = 0; i < 4; ++i) {
        int idx = tid + 256 * i;
        sx4[idx] = (idx < maxq) ? xb[idx] : make_float4(0.f, 0.f, 0.f, 0.f);
    }
    __syncthreads();
    int r0 = tid >> 4;     // row group 0..15
    int cq = tid & 15;     // col quad
    float4 a0 = make_float4(0,0,0,0), a1 = a0, a2 = a0, a3 = a0;
#pragma unroll
    for (int k4 = 0; k4 < 16; ++k4) {
        float4 w0 = sW4[(k4 * 4 + 0) * 16 + cq];
        float4 w1 = sW4[(k4 * 4 + 1) * 16 + cq];
        float4 w2 = sW4[(k4 * 4 + 2) * 16 + cq];
        float4 w3 = sW4[(k4 * 4 + 3) * 16 + cq];
        float4 xv;
        xv = sx4[(r0 +  0) * 16 + k4];
        a0.x += xv.x*w0.x + xv.y*w1.x + xv.z*w2.x + xv.w*w3.x;
        a0.y += xv.x*w0.y + xv.y*w1.y + xv.z*w2.y + xv.w*w3.y;
        a0.z += xv.x*w0.z + xv.y*w1.z + xv.z*w2.z + xv.w*w3.z;
        a0.w += xv.x*w0.w + xv.y*w1.w + xv.z*w2.w + xv.w*w3.w;
        xv = sx4[(r0 + 16) * 16 + k4];
        a1.x += xv.x*w0.x + xv.y*w1.x + xv.z*w2.x + xv.w*w3.x;
        a1.y += xv.x*w0.y + xv.y*w1.y + xv.z*w2.y + xv.w*w3.y;
        a1.z += xv.x*w0.z + xv.y*w1.z + xv.z*w2.z + xv.w*w3.z;
        a1.w += xv.x*w0.w + xv.y*w1.w + xv.z*w2.w + xv.w*w3.w;
        xv = sx4[(r0 + 32) * 16 + k4];
        a2.x += xv.x*w0.x + xv.y*w1.x + xv.z*w2.x + xv.w*w3.x;
        a2.y += xv.x*w0.y + xv.y*w1.y + xv.z*w2.y + xv.w*w3.y;
        a2.z += xv.x*w0.z + xv.y*w1.z + xv.z*w2.z + xv.w*w3.z;
        a2.w += xv.x*w0.w + xv.y*w1.w + xv.z*w2.w + xv.w*w3.w;
        xv = sx4[(r0 + 48) * 16 + k4];
        a3.x += xv.x*w0.x + xv.y*w1.x + xv.z*w2.x + xv.w*w3.x;
        a3.y += xv.x*w0.y + xv.y*w1.y + xv.z*w2.y + xv.w*w3.y;
        a3.z += xv.x*w0.z + xv.y*w1.z + xv.z*w2.z + xv.w*w3.z;
        a3.w += xv.x*w0.w + xv.y*w1.w + xv.z*w2.w + xv.w*w3.w;
    }
    float4 acc[4] = {a0, a1, a2, a3};
#pragma unroll
    for (int rr = 0; rr < 4; ++rr) {
        int row = rowbase + r0 + 16 * rr;
        if (row < N_NODES) {
            float dv = dinv[row];
            out[(size_t)row * 16 + cq] =
                f4_to_h4(make_float4(acc[rr].x * dv, acc[rr].y * dv,
                                     acc[rr].z * dv, acc[rr].w * dv));
        }
    }
}

// ---------------- layer-1 gather (fp16 in) -> h fp16: lean, latency-optimized ----------------
// 16 lanes per node (4 dims each), 4 nodes per wave, 16 nodes per block.
__global__ __launch_bounds__(256) void k_gather64(const float2* __restrict__ xlph,
                                                  const unsigned short* __restrict__ csr_src,
                                                  const int* __restrict__ off,
                                                  const float* __restrict__ dinv,
                                                  const float* __restrict__ b1,
                                                  float2* __restrict__ hh /* fp16x4 */) {
    int node = blockIdx.x * 16 + (threadIdx.x >> 4);   // 50000 = 16*3125 exact
    int d4 = threadIdx.x & 15;
    int beg = off[node], end = off[node + 1];
    float4 acc = h4_to_f4(xlph[(size_t)node * 16 + d4]);   // self-loop (dinv folded in)
    int j = beg;
    for (; j + 8 <= end; j += 8) {                     // 8-deep per lane chain
        int s0 = csr_src[j],     s1 = csr_src[j + 1];
        int s2 = csr_src[j + 2], s3 = csr_src[j + 3];
        int s4 = csr_src[j + 4], s5 = csr_src[j + 5];
        int s6 = csr_src[j + 6], s7 = csr_src[j + 7];
        float2 r0 = xlph[(size_t)s0 * 16 + d4];
        float2 r1 = xlph[(size_t)s1 * 16 + d4];
        float2 r2 = xlph[(size_t)s2 * 16 + d4];
        float2 r3 = xlph[(size_t)s3 * 16 + d4];
        float2 r4 = xlph[(size_t)s4 * 16 + d4];
        float2 r5 = xlph[(size_t)s5 * 16 + d4];
        float2 r6 = xlph[(size_t)s6 * 16 + d4];
        float2 r7 = xlph[(size_t)s7 * 16 + d4];
        float4 v0 = h4_to_f4(r0), v1 = h4_to_f4(r1);
        float4 v2 = h4_to_f4(r2), v3 = h4_to_f4(r3);
        float4 v4 = h4_to_f4(r4), v5 = h4_to_f4(r5);
        float4 v6 = h4_to_f4(r6), v7 = h4_to_f4(r7);
        acc.x += ((v0.x + v1.x) + (v2.x + v3.x)) + ((v4.x + v5.x) + (v6.x + v7.x));
        acc.y += ((v0.y + v1.y) + (v2.y + v3.y)) + ((v4.y + v5.y) + (v6.y + v7.y));
        acc.z += ((v0.z + v1.z) + (v2.z + v3.z)) + ((v4.z + v5.z) + (v6.z + v7.z));
        acc.w += ((v0.w + v1.w) + (v2.w + v3.w)) + ((v4.w + v5.w) + (v6.w + v7.w));
    }
    for (; j + 4 <= end; j += 4) {
        int s0 = csr_src[j],     s1 = csr_src[j + 1];
        int s2 = csr_src[j + 2], s3 = csr_src[j + 3];
        float4 v0 = h4_to_f4(xlph[(size_t)s0 * 16 + d4]);
        float4 v1 = h4_to_f4(xlph[(size_t)s1 * 16 + d4]);
        float4 v2 = h4_to_f4(xlph[(size_t)s2 * 16 + d4]);
        float4 v3 = h4_to_f4(xlph[(size_t)s3 * 16 + d4]);
        acc.x += (v0.x + v1.x) + (v2.x + v3.x);
        acc.y += (v0.y + v1.y) + (v2.y + v3.y);
        acc.z += (v0.z + v1.z) + (v2.z + v3.z);
        acc.w += (v0.w + v1.w) + (v2.w + v3.w);
    }
    for (; j < end; ++j) {
        float4 v = h4_to_f4(xlph[(size_t)csr_src[j] * 16 + d4]);
        acc.x += v.x; acc.y += v.y; acc.z += v.z; acc.w += v.w;
    }
    float dv = dinv[node];
    float4 bb = ((const float4*)b1)[d4];
    float4 r;
    r.x = fmaxf(dv * acc.x + bb.x, 0.0f);
    r.y = fmaxf(dv * acc.y + bb.y, 0.0f);
    r.z = fmaxf(dv * acc.z + bb.z, 0.0f);
    r.w = fmaxf(dv * acc.w + bb.w, 0.0f);
    hh[(size_t)node * 16 + d4] = f4_to_h4(r);
}

// ---------------- hl' = (h @ W2) * dinv[row] — 25-row tile, h fp16 staged to LDS fp32 ----------------
// block 256; grid 2000 exact (25 rows/block, 250 output threads).
__global__ __launch_bounds__(256) void k_xw10(const float2* __restrict__ hh /* fp16x4 */,
                                              const float* __restrict__ W,
                                              const float* __restrict__ dinv,
                                              float* __restrict__ out) {
    __shared__ float sW[HID_DIM * N_CLS];   // 2.5 KB
    __shared__ float4 sh4[25 * 16];         // 25 rows x 16 quads fp32 (6.25 KB)
    int tid = threadIdx.x;
    for (int i = tid; i < HID_DIM * N_CLS; i += 256) sW[i] = W[i];
    int rowbase = blockIdx.x * 25;
    const float2* hb = hh + (size_t)rowbase * 16;
    for (int i = tid; i < 25 * 16; i += 256) sh4[i] = h4_to_f4(hb[i]);  // coalesced 8B
    __syncthreads();
    if (tid >= 250) return;
    int r = tid / N_CLS;
    int col = tid - r * N_CLS;
    const float* hr = (const float*)&sh4[r * 16];
    float acc = 0.0f;
#pragma unroll
    for (int k = 0; k < HID_DIM; ++k) acc += hr[k] * sW[k * N_CLS + col];
    int row = rowbase + r;
    out[(size_t)row * N_CLS + col] = acc * dinv[row];
}

// ---------------- layer-2 gather + b2 + log_softmax, 16-lane group per node ----------------
__global__ __launch_bounds__(256) void k_gather10(const float* __restrict__ hlp,
                                                  const unsigned short* __restrict__ csr_src,
                                                  const int* __restrict__ off,
                                                  const float* __restrict__ dinv,
                                                  const float* __restrict__ b2,
                                                  float* __restrict__ out) {
    int t = threadIdx.x;
    int node = blockIdx.x * 16 + (t >> 4);
    int d = t & 15;
    bool act = d < N_CLS;
    int dd = act ? d : 0;
    int beg = off[node], end = off[node + 1];
    float acc = act ? hlp[(size_t)node * N_CLS + d] : 0.0f;
    int j = beg;
    for (; j + 8 <= end; j += 8) {
        int s0 = csr_src[j],     s1 = csr_src[j + 1];
        int s2 = csr_src[j + 2], s3 = csr_src[j + 3];
        int s4 = csr_src[j + 4], s5 = csr_src[j + 5];
        int s6 = csr_src[j + 6], s7 = csr_src[j + 7];
        float v0 = hlp[(size_t)s0 * N_CLS + dd];
        float v1 = hlp[(size_t)s1 * N_CLS + dd];
        float v2 = hlp[(size_t)s2 * N_CLS + dd];
        float v3 = hlp[(size_t)s3 * N_CLS + dd];
        float v4 = hlp[(size_t)s4 * N_CLS + dd];
        float v5 = hlp[(size_t)s5 * N_CLS + dd];
        float v6 = hlp[(size_t)s6 * N_CLS + dd];
        float v7 = hlp[(size_t)s7 * N_CLS + dd];
        if (act) acc += ((v0 + v1) + (v2 + v3)) + ((v4 + v5) + (v6 + v7));
    }
    for (; j + 4 <= end; j += 4) {
        int s0 = csr_src[j],     s1 = csr_src[j + 1];
        int s2 = csr_src[j + 2], s3 = csr_src[j + 3];
        float v0 = hlp[(size_t)s0 * N_CLS + dd];
        float v1 = hlp[(size_t)s1 * N_CLS + dd];
        float v2 = hlp[(size_t)s2 * N_CLS + dd];
        float v3 = hlp[(size_t)s3 * N_CLS + dd];
        if (act) acc += (v0 + v1) + (v2 + v3);
    }
    for (; j < end; ++j) {
        float v = hlp[(size_t)csr_src[j] * N_CLS + dd];
        if (act) acc += v;
    }
    float v = act ? dinv[node] * acc + b2[d] : -INFINITY;
    float m = v;
#pragma unroll
    for (int k = 1; k < 16; k <<= 1) m = fmaxf(m, __shfl_xor(m, k, 64));
    float ex = act ? expf(v - m) : 0.0f;
    float ssum = ex;
#pragma unroll
    for (int k = 1; k < 16; k <<= 1) ssum += __shfl_xor(ssum, k, 64);
    if (act) out[(size_t)node * N_CLS + d] = v - m - logf(ssum);
}

extern "C" void kernel_launch(void* const* d_in, const int* in_sizes, int n_in,
                              void* d_out, int out_size, void* d_ws, size_t ws_size,
                              hipStream_t stream) {
    const float* x  = (const float*)d_in[0];
    const int*   ei = (const int*)d_in[1];
    const float* W1 = (const float*)d_in[2];
    const float* b1 = (const float*)d_in[3];
    const float* W2 = (const float*)d_in[4];
    const float* b2 = (const float*)d_in[5];
    float* out = (float*)d_out;

    const int* src = ei;             // edge_index[0]
    const int* dst = ei + N_EDGES;   // edge_index[1]

    // workspace layout (all segment starts 16B-aligned)
    int*            bhist   = (int*)d_ws;                   // 12544 (pad 12800)
    int*            bbase   = bhist + 12800;                // 197  (pad 256)
    int*            off     = bbase + 256;                  // 50001 (pad 50432)
    int*            packed  = off + 50432;                  // 800000
    unsigned short* csr16   = (unsigned short*)(packed + N_EDGES);  // 800000 ushort (1.6 MB)
    float*          dinv    = (float*)(csr16 + N_EDGES);    // 50000 (pad 50048)
    float2*         xlh     = (float2*)(dinv + 50048);      // fp16 xl': 800000 float2 (6.4 MB)
    float2*         hh      = xlh + (size_t)N_NODES * 16;   // fp16 h: 800000 float2 (6.4 MB)
    float*          hl      = (float*)(hh + (size_t)N_NODES * 16);  // fp32 hl': 500000 (2 MB)

    const int B = 256;
    int g_x64 = (N_NODES + 63) / 64;              // 782
    int g_x10 = N_NODES / 25;                     // 2000 exact
    int g_g16 = N_NODES / 16;                     // 3125 exact

    k_chist    <<<PBLK,  1024, 0, stream>>>(dst, bhist);
    k_cscan    <<<1,     1024, 0, stream>>>(bhist, bbase, off);
    k_partition<<<PBLK,  1024, 0, stream>>>(src, dst, bhist, packed);
    k_fine     <<<NBUCK, 1024, 0, stream>>>(packed, bbase, off, dinv, csr16);
    k_xw64     <<<g_x64,   B, 0, stream>>>(x, W1, dinv, xlh);
    k_gather64 <<<g_g16,   B, 0, stream>>>(xlh, csr16, off, dinv, b1, hh);
    k_xw10     <<<g_x10,   B, 0, stream>>>(hh, W2, dinv, hl);
    k_gather10 <<<g_g16,   B, 0, stream>>>(hl, csr16, off, dinv, b2, out);
    (void)in_sizes; (void)n_in; (void)out_size; (void)ws_size;
}

// Round 13
// 156.872 us; speedup vs baseline: 1.0852x; 1.0852x over previous
//
#include <hip/hip_runtime.h>
#include <hip/hip_fp16.h>
#include <math.h>

#define N_NODES  50000
#define N_EDGES  800000
#define IN_DIM   64
#define HID_DIM  64
#define N_CLS    10
#define NBUCK    196      // ceil(N_NODES/256) coarse buckets (dst >> 8)
#define PBLK     64       // partition blocks
#define PCHUNK   (N_EDGES / PBLK)   // 12500 edges per partition block (exact)
#define SCANTOT  (NBUCK * PBLK)     // 12544
#define FCAP     8192     // k_fine LDS edge cache capacity (32 KB)

// unpack 4 fp16 (carried in a float2) to float4
__device__ __forceinline__ float4 h4_to_f4(float2 raw) {
    union { float2 f; __half2 h[2]; } u;
    u.f = raw;
    float2 lo = __half22float2(u.h[0]);
    float2 hi = __half22float2(u.h[1]);
    return make_float4(lo.x, lo.y, hi.x, hi.y);
}

// ---------------- pass 1a: per-block coarse histogram (dst>>8) ----------------
__global__ __launch_bounds__(1024) void k_chist(const int* __restrict__ dst,
                                                int* __restrict__ bhist) {
    __shared__ int lh[NBUCK];
    int t = threadIdx.x;
    for (int i = t; i < NBUCK; i += 1024) lh[i] = 0;
    __syncthreads();
    int beg = blockIdx.x * PCHUNK, end = beg + PCHUNK;
    for (int e = beg + t; e < end; e += 1024)
        atomicAdd(&lh[dst[e] >> 8], 1);          // LDS atomic
    __syncthreads();
    for (int i = t; i < NBUCK; i += 1024)
        bhist[i * PBLK + blockIdx.x] = lh[i];    // bin-major
}

// ---------------- pass 1b: scan 12544 (bin,block) counts in LDS ----------------
__global__ __launch_bounds__(1024) void k_cscan(int* __restrict__ bhist,
                                                int* __restrict__ bbase,
                                                int* __restrict__ off) {
    __shared__ int s[SCANTOT];
    __shared__ int tsum[1024];
    int t = threadIdx.x;
    for (int i = t; i < SCANTOT; i += 1024) s[i] = bhist[i];   // coalesced
    __syncthreads();
    const int IT = (SCANTOT + 1023) / 1024;  // 13
    int base_i = t * IT;
    int sum = 0;
    for (int j = 0; j < IT; ++j) {
        int i = base_i + j;
        if (i < SCANTOT) sum += s[i];
    }
    tsum[t] = sum;
    __syncthreads();
    for (int d = 1; d < 1024; d <<= 1) {
        int v = (t >= d) ? tsum[t - d] : 0;
        __syncthreads();
        if (t >= d) tsum[t] += v;
        __syncthreads();
    }
    int run = (t > 0) ? tsum[t - 1] : 0;
    for (int j = 0; j < IT; ++j) {
        int i = base_i + j;
        if (i < SCANTOT) { int c = s[i]; s[i] = run; run += c; }
    }
    __syncthreads();
    for (int i = t; i < SCANTOT; i += 1024) bhist[i] = s[i];
    for (int i = t; i < NBUCK; i += 1024) bbase[i] = s[i * PBLK];
    if (t == 0) { bbase[NBUCK] = N_EDGES; off[N_NODES] = N_EDGES; }
}

// ---------------- pass 1c: partition edges into coarse buckets (packed) ----------------
__global__ __launch_bounds__(1024) void k_partition(const int* __restrict__ src,
                                                    const int* __restrict__ dst,
                                                    const int* __restrict__ bhist,
                                                    int* __restrict__ packed) {
    __shared__ int cur[NBUCK];
    int t = threadIdx.x;
    for (int i = t; i < NBUCK; i += 1024)
        cur[i] = bhist[i * PBLK + blockIdx.x];
    __syncthreads();
    int beg = blockIdx.x * PCHUNK, end = beg + PCHUNK;
    for (int e = beg + t; e < end; e += 1024) {
        int d = dst[e], sv = src[e];
        int slot = atomicAdd(&cur[d >> 8], 1);          // LDS atomic
        packed[slot] = ((d & 255) << 16) | sv;          // run-contiguous per (blk,bin)
    }
}

// ---------------- pass 2: per-bucket fine CSR + off + dinv (LDS edge cache) ----------------
__global__ __launch_bounds__(1024) void k_fine(const int* __restrict__ packed,
                                               const int* __restrict__ bbase,
                                               int* __restrict__ off,
                                               float* __restrict__ dinv,
                                               int* __restrict__ csr_src) {
    __shared__ int hist[256];
    __shared__ int scan[256];
    __shared__ int cur[256];
    __shared__ int ecache[FCAP];            // 32 KB
    int t = threadIdx.x;
    int bucket = blockIdx.x;
    if (t < 256) hist[t] = 0;
    __syncthreads();
    int beg = bbase[bucket], end = bbase[bucket + 1];
    int ne = end - beg;
    bool cached = ne <= FCAP;
    if (cached) {
        for (int i = t; i < ne; i += 1024) {
            int p = packed[beg + i];
            ecache[i] = p;
            atomicAdd(&hist[p >> 16], 1);
        }
    } else {
        for (int i = beg + t; i < end; i += 1024)
            atomicAdd(&hist[packed[i] >> 16], 1);
    }
    __syncthreads();
    if (t < 256) scan[t] = hist[t];
    __syncthreads();
    for (int d = 1; d < 256; d <<= 1) {
        int v = 0;
        if (t < 256 && t >= d) v = scan[t - d];
        __syncthreads();
        if (t < 256 && t >= d) scan[t] += v;
        __syncthreads();
    }
    if (t < 256) {
        int excl = beg + scan[t] - hist[t];
        cur[t] = excl;
        int node = bucket * 256 + t;
        if (node < N_NODES) {
            off[node] = excl;
            dinv[node] = rsqrtf((float)(hist[t] + 1));   // +1 self-loop
        }
    }
    __syncthreads();
    if (cached) {
        for (int i = t; i < ne; i += 1024) {
            int p = ecache[i];
            int slot = atomicAdd(&cur[p >> 16], 1);      // LDS atomic
            csr_src[slot] = p & 0xFFFF;
        }
    } else {
        for (int i = beg + t; i < end; i += 1024) {
            int p = packed[i];
            int slot = atomicAdd(&cur[p >> 16], 1);
            csr_src[slot] = p & 0xFFFF;
        }
    }
}

// ---------------- xl' = fp16((x @ W1) * dinv[row]) — 16-row tile, all-LDS inner loop ----------------
// block 256 = 16 rows x 16 col-quads; grid 3125 exact. Output fp16 (8 B per thread).
__global__ __launch_bounds__(256) void k_xw64(const float* __restrict__ x,
                                              const float* __restrict__ W,
                                              const float* __restrict__ dinv,
                                              float2* __restrict__ out /* fp16x4 */) {
    __shared__ float4 sW4[IN_DIM * 16];   // W1: 64 rows x 16 col-quads (16 KB)
    __shared__ float4 sx4[16 * 16];       // x tile: 16 rows x 16 k-quads (4 KB)
    int tid = threadIdx.x;
    const float4* W4 = (const float4*)W;
#pragma unroll
    for (int i = 0; i < 4; ++i) sW4[tid + 256 * i] = W4[tid + 256 * i];
    int rowbase = blockIdx.x * 16;
    sx4[tid] = ((const float4*)(x + (size_t)rowbase * IN_DIM))[tid];  // coalesced
    __syncthreads();
    int r  = tid >> 4;     // row in tile
    int cq = tid & 15;     // col quad
    const float4* sxr = &sx4[r * 16];
    float ax = 0.0f, ay = 0.0f, az = 0.0f, aw = 0.0f;
#pragma unroll
    for (int k4 = 0; k4 < 16; ++k4) {
        float4 xv = sxr[k4];
        float4 w0 = sW4[(k4 * 4 + 0) * 16 + cq];
        float4 w1 = sW4[(k4 * 4 + 1) * 16 + cq];
        float4 w2 = sW4[(k4 * 4 + 2) * 16 + cq];
        float4 w3 = sW4[(k4 * 4 + 3) * 16 + cq];
        ax += xv.x * w0.x + xv.y * w1.x + xv.z * w2.x + xv.w * w3.x;
        ay += xv.x * w0.y + xv.y * w1.y + xv.z * w2.y + xv.w * w3.y;
        az += xv.x * w0.z + xv.y * w1.z + xv.z * w2.z + xv.w * w3.z;
        aw += xv.x * w0.w + xv.y * w1.w + xv.z * w2.w + xv.w * w3.w;
    }
    int row = rowbase + r;
    float dv = dinv[row];
    union { __half2 h[2]; float2 f; } u;
    u.h[0] = __floats2half2_rn(ax * dv, ay * dv);
    u.h[1] = __floats2half2_rn(az * dv, aw * dv);
    out[(size_t)row * 16 + cq] = u.f;
}

// ---------------- layer-1 gather (fp16x4): h = relu(dinv*(self+sum)+b1) ----------------
// 16 lanes per node (4 fp16 dims each), 4 nodes per wave, 16 nodes per block.
__global__ __launch_bounds__(256) void k_gather64(const float2* __restrict__ xlph,
                                                  const int* __restrict__ csr_src,
                                                  const int* __restrict__ off,
                                                  const float* __restrict__ dinv,
                                                  const float* __restrict__ b1,
                                                  float* __restrict__ h) {
    int node = blockIdx.x * 16 + (threadIdx.x >> 4);   // 50000 = 16*3125 exact
    int d4 = threadIdx.x & 15;
    int beg = off[node], end = off[node + 1];
    float4 acc = h4_to_f4(xlph[(size_t)node * 16 + d4]);   // self-loop (dinv folded in)
    int j = beg;
    for (; j + 8 <= end; j += 8) {                     // 8-deep per lane chain
        int s0 = csr_src[j],     s1 = csr_src[j + 1];
        int s2 = csr_src[j + 2], s3 = csr_src[j + 3];
        int s4 = csr_src[j + 4], s5 = csr_src[j + 5];
        int s6 = csr_src[j + 6], s7 = csr_src[j + 7];
        float2 r0 = xlph[(size_t)s0 * 16 + d4];
        float2 r1 = xlph[(size_t)s1 * 16 + d4];
        float2 r2 = xlph[(size_t)s2 * 16 + d4];
        float2 r3 = xlph[(size_t)s3 * 16 + d4];
        float2 r4 = xlph[(size_t)s4 * 16 + d4];
        float2 r5 = xlph[(size_t)s5 * 16 + d4];
        float2 r6 = xlph[(size_t)s6 * 16 + d4];
        float2 r7 = xlph[(size_t)s7 * 16 + d4];
        float4 v0 = h4_to_f4(r0), v1 = h4_to_f4(r1);
        float4 v2 = h4_to_f4(r2), v3 = h4_to_f4(r3);
        float4 v4 = h4_to_f4(r4), v5 = h4_to_f4(r5);
        float4 v6 = h4_to_f4(r6), v7 = h4_to_f4(r7);
        acc.x += ((v0.x + v1.x) + (v2.x + v3.x)) + ((v4.x + v5.x) + (v6.x + v7.x));
        acc.y += ((v0.y + v1.y) + (v2.y + v3.y)) + ((v4.y + v5.y) + (v6.y + v7.y));
        acc.z += ((v0.z + v1.z) + (v2.z + v3.z)) + ((v4.z + v5.z) + (v6.z + v7.z));
        acc.w += ((v0.w + v1.w) + (v2.w + v3.w)) + ((v4.w + v5.w) + (v6.w + v7.w));
    }
    for (; j + 4 <= end; j += 4) {
        int s0 = csr_src[j],     s1 = csr_src[j + 1];
        int s2 = csr_src[j + 2], s3 = csr_src[j + 3];
        float4 v0 = h4_to_f4(xlph[(size_t)s0 * 16 + d4]);
        float4 v1 = h4_to_f4(xlph[(size_t)s1 * 16 + d4]);
        float4 v2 = h4_to_f4(xlph[(size_t)s2 * 16 + d4]);
        float4 v3 = h4_to_f4(xlph[(size_t)s3 * 16 + d4]);
        acc.x += (v0.x + v1.x) + (v2.x + v3.x);
        acc.y += (v0.y + v1.y) + (v2.y + v3.y);
        acc.z += (v0.z + v1.z) + (v2.z + v3.z);
        acc.w += (v0.w + v1.w) + (v2.w + v3.w);
    }
    for (; j < end; ++j) {
        float4 v = h4_to_f4(xlph[(size_t)csr_src[j] * 16 + d4]);
        acc.x += v.x; acc.y += v.y; acc.z += v.z; acc.w += v.w;
    }
    float dv = dinv[node];
    float4 bb = ((const float4*)b1)[d4];
    float4 r;
    r.x = fmaxf(dv * acc.x + bb.x, 0.0f);
    r.y = fmaxf(dv * acc.y + bb.y, 0.0f);
    r.z = fmaxf(dv * acc.z + bb.z, 0.0f);
    r.w = fmaxf(dv * acc.w + bb.w, 0.0f);
    ((float4*)h)[(size_t)node * 16 + d4] = r;
}

// ---------------- hl' = fp16((h @ W2) * dinv[row]) — 25-row tile, all-LDS inner loop ----------------
// block 256; grid 2000 exact (25 rows/block, 250 output threads).
__global__ __launch_bounds__(256) void k_xw10(const float* __restrict__ h,
                                              const float* __restrict__ W,
                                              const float* __restrict__ dinv,
                                              __half* __restrict__ out /* fp16, stride 10 */) {
    __shared__ float sW[HID_DIM * N_CLS];   // 2.5 KB
    __shared__ float4 sh4[25 * 16];         // 25 rows x 16 quads (6.25 KB)
    int tid = threadIdx.x;
    for (int i = tid; i < HID_DIM * N_CLS; i += 256) sW[i] = W[i];
    int rowbase = blockIdx.x * 25;
    const float4* hb = (const float4*)(h + (size_t)rowbase * HID_DIM);
    for (int i = tid; i < 25 * 16; i += 256) sh4[i] = hb[i];   // coalesced
    __syncthreads();
    if (tid >= 250) return;
    int r = tid / N_CLS;
    int col = tid - r * N_CLS;
    const float* hr = (const float*)&sh4[r * 16];
    float acc = 0.0f;
#pragma unroll
    for (int k = 0; k < HID_DIM; ++k) acc += hr[k] * sW[k * N_CLS + col];
    int row = rowbase + r;
    out[(size_t)row * N_CLS + col] = __float2half(acc * dinv[row]);
}

// ---------------- layer-2 gather (fp16 hl) + b2 + log_softmax, 16-lane group per node ----------------
__global__ __launch_bounds__(256) void k_gather10(const __half* __restrict__ hlh,
                                                  const int* __restrict__ csr_src,
                                                  const int* __restrict__ off,
                                                  const float* __restrict__ dinv,
                                                  const float* __restrict__ b2,
                                                  float* __restrict__ out) {
    int t = threadIdx.x;
    int node = blockIdx.x * 16 + (t >> 4);
    int d = t & 15;
    bool act = d < N_CLS;
    int dd = act ? d : 0;
    int beg = off[node], end = off[node + 1];
    float acc = act ? __half2float(hlh[(size_t)node * N_CLS + d]) : 0.0f;
    int j = beg;
    for (; j + 8 <= end; j += 8) {
        int s0 = csr_src[j],     s1 = csr_src[j + 1];
        int s2 = csr_src[j + 2], s3 = csr_src[j + 3];
        int s4 = csr_src[j + 4], s5 = csr_src[j + 5];
        int s6 = csr_src[j + 6], s7 = csr_src[j + 7];
        float v0 = __half2float(hlh[(size_t)s0 * N_CLS + dd]);
        float v1 = __half2float(hlh[(size_t)s1 * N_CLS + dd]);
        float v2 = __half2float(hlh[(size_t)s2 * N_CLS + dd]);
        float v3 = __half2float(hlh[(size_t)s3 * N_CLS + dd]);
        float v4 = __half2float(hlh[(size_t)s4 * N_CLS + dd]);
        float v5 = __half2float(hlh[(size_t)s5 * N_CLS + dd]);
        float v6 = __half2float(hlh[(size_t)s6 * N_CLS + dd]);
        float v7 = __half2float(hlh[(size_t)s7 * N_CLS + dd]);
        if (act) acc += ((v0 + v1) + (v2 + v3)) + ((v4 + v5) + (v6 + v7));
    }
    for (; j + 4 <= end; j += 4) {
        int s0 = csr_src[j],     s1 = csr_src[j + 1];
        int s2 = csr_src[j + 2], s3 = csr_src[j + 3];
        float v0 = __half2float(hlh[(size_t)s0 * N_CLS + dd]);
        float v1 = __half2float(hlh[(size_t)s1 * N_CLS + dd]);
        float v2 = __half2float(hlh[(size_t)s2 * N_CLS + dd]);
        float v3 = __half2float(hlh[(size_t)s3 * N_CLS + dd]);
        if (act) acc += (v0 + v1) + (v2 + v3);
    }
    for (; j < end; ++j) {
        float v = __half2float(hlh[(size_t)csr_src[j] * N_CLS + dd]);
        if (act) acc += v;
    }
    float v = act ? dinv[node] * acc + b2[d] : -INFINITY;
    float m = v;
#pragma unroll
    for (int k = 1; k < 16; k <<= 1) m = fmaxf(m, __shfl_xor(m, k, 64));
    float ex = act ? expf(v - m) : 0.0f;
    float ssum = ex;
#pragma unroll
    for (int k = 1; k < 16; k <<= 1) ssum += __shfl_xor(ssum, k, 64);
    if (act) out[(size_t)node * N_CLS + d] = v - m - logf(ssum);
}

extern "C" void kernel_launch(void* const* d_in, const int* in_sizes, int n_in,
                              void* d_out, int out_size, void* d_ws, size_t ws_size,
                              hipStream_t stream) {
    const float* x  = (const float*)d_in[0];
    const int*   ei = (const int*)d_in[1];
    const float* W1 = (const float*)d_in[2];
    const float* b1 = (const float*)d_in[3];
    const float* W2 = (const float*)d_in[4];
    const float* b2 = (const float*)d_in[5];
    float* out = (float*)d_out;

    const int* src = ei;             // edge_index[0]
    const int* dst = ei + N_EDGES;   // edge_index[1]

    // workspace layout (all segment starts 16B-aligned) — identical to R10
    int*    bhist   = (int*)d_ws;                  // 12544 (pad 12800)
    int*    bbase   = bhist + 12800;               // 197  (pad 256)
    int*    off     = bbase + 256;                 // 50001 (pad 50432)
    int*    packed  = off + 50432;                 // 800000
    int*    csr_src = packed + N_EDGES;            // 800000 (int, as in R10)
    float*  dinv    = (float*)(csr_src + N_EDGES); // 50000 (pad 50048)
    float2* xlh     = (float2*)(dinv + 50048);     // fp16 xl': 800000 float2 (6.4 MB)
    float*  h       = (float*)(xlh + (size_t)N_NODES * 16); // 3,200,000 floats
    __half* hlh     = (__half*)xlh;                // fp16 hl': 500000 halfs, aliases dead xlh

    const int B = 256;
    int g_x64 = N_NODES / 16;                     // 3125 exact
    int g_x10 = N_NODES / 25;                     // 2000 exact
    int g_g16 = N_NODES / 16;                     // 3125 exact

    k_chist    <<<PBLK,  1024, 0, stream>>>(dst, bhist);
    k_cscan    <<<1,     1024, 0, stream>>>(bhist, bbase, off);
    k_partition<<<PBLK,  1024, 0, stream>>>(src, dst, bhist, packed);
    k_fine     <<<NBUCK, 1024, 0, stream>>>(packed, bbase, off, dinv, csr_src);
    k_xw64     <<<g_x64,   B, 0, stream>>>(x, W1, dinv, xlh);
    k_gather64 <<<g_g16,   B, 0, stream>>>(xlh, csr_src, off, dinv, b1, h);
    k_xw10     <<<g_x10,   B, 0, stream>>>(h, W2, dinv, hlh);
    k_gather10 <<<g_g16,   B, 0, stream>>>(hlh, csr_src, off, dinv, b2, out);
    (void)in_sizes; (void)n_in; (void)out_size; (void)ws_size;
}

// Round 14
// 154.223 us; speedup vs baseline: 1.1039x; 1.0172x over previous
//
#include <hip/hip_runtime.h>
#include <hip/hip_fp16.h>
#include <math.h>

#define N_NODES  50000
#define N_EDGES  800000
#define IN_DIM   64
#define HID_DIM  64
#define N_CLS    10
#define NBUCK    196      // ceil(N_NODES/256) coarse buckets (dst >> 8)
#define PBLK     64       // partition blocks
#define PCHUNK   (N_EDGES / PBLK)   // 12500 edges per partition block (exact)
#define SCANTOT  (NBUCK * PBLK)     // 12544
#define FCAP     8192     // k_fine LDS edge cache capacity (32 KB)

// unpack 4 fp16 (carried in a float2) to float4
__device__ __forceinline__ float4 h4_to_f4(float2 raw) {
    union { float2 f; __half2 h[2]; } u;
    u.f = raw;
    float2 lo = __half22float2(u.h[0]);
    float2 hi = __half22float2(u.h[1]);
    return make_float4(lo.x, lo.y, hi.x, hi.y);
}

// ---------------- pass 1a: per-block coarse histogram (dst>>8) ----------------
__global__ __launch_bounds__(1024) void k_chist(const int* __restrict__ dst,
                                                int* __restrict__ bhist) {
    __shared__ int lh[NBUCK];
    int t = threadIdx.x;
    for (int i = t; i < NBUCK; i += 1024) lh[i] = 0;
    __syncthreads();
    int beg = blockIdx.x * PCHUNK, end = beg + PCHUNK;
    for (int e = beg + t; e < end; e += 1024)
        atomicAdd(&lh[dst[e] >> 8], 1);          // LDS atomic
    __syncthreads();
    for (int i = t; i < NBUCK; i += 1024)
        bhist[i * PBLK + blockIdx.x] = lh[i];    // bin-major
}

// ---------------- pass 1b: scan 12544 (bin,block) counts in LDS ----------------
__global__ __launch_bounds__(1024) void k_cscan(int* __restrict__ bhist,
                                                int* __restrict__ bbase,
                                                int* __restrict__ off) {
    __shared__ int s[SCANTOT];
    __shared__ int tsum[1024];
    int t = threadIdx.x;
    for (int i = t; i < SCANTOT; i += 1024) s[i] = bhist[i];   // coalesced
    __syncthreads();
    const int IT = (SCANTOT + 1023) / 1024;  // 13
    int base_i = t * IT;
    int sum = 0;
    for (int j = 0; j < IT; ++j) {
        int i = base_i + j;
        if (i < SCANTOT) sum += s[i];
    }
    tsum[t] = sum;
    __syncthreads();
    for (int d = 1; d < 1024; d <<= 1) {
        int v = (t >= d) ? tsum[t - d] : 0;
        __syncthreads();
        if (t >= d) tsum[t] += v;
        __syncthreads();
    }
    int run = (t > 0) ? tsum[t - 1] : 0;
    for (int j = 0; j < IT; ++j) {
        int i = base_i + j;
        if (i < SCANTOT) { int c = s[i]; s[i] = run; run += c; }
    }
    __syncthreads();
    for (int i = t; i < SCANTOT; i += 1024) bhist[i] = s[i];
    for (int i = t; i < NBUCK; i += 1024) bbase[i] = s[i * PBLK];
    if (t == 0) { bbase[NBUCK] = N_EDGES; off[N_NODES] = N_EDGES; }
}

// ---------------- pass 1c: partition edges into coarse buckets (packed) ----------------
__global__ __launch_bounds__(1024) void k_partition(const int* __restrict__ src,
                                                    const int* __restrict__ dst,
                                                    const int* __restrict__ bhist,
                                                    int* __restrict__ packed) {
    __shared__ int cur[NBUCK];
    int t = threadIdx.x;
    for (int i = t; i < NBUCK; i += 1024)
        cur[i] = bhist[i * PBLK + blockIdx.x];
    __syncthreads();
    int beg = blockIdx.x * PCHUNK, end = beg + PCHUNK;
    for (int e = beg + t; e < end; e += 1024) {
        int d = dst[e], sv = src[e];
        int slot = atomicAdd(&cur[d >> 8], 1);          // LDS atomic
        packed[slot] = ((d & 255) << 16) | sv;          // run-contiguous per (blk,bin)
    }
}

// ---------------- pass 2: per-bucket fine CSR + off + dinv (LDS edge cache) ----------------
__global__ __launch_bounds__(1024) void k_fine(const int* __restrict__ packed,
                                               const int* __restrict__ bbase,
                                               int* __restrict__ off,
                                               float* __restrict__ dinv,
                                               int* __restrict__ csr_src) {
    __shared__ int hist[256];
    __shared__ int scan[256];
    __shared__ int cur[256];
    __shared__ int ecache[FCAP];            // 32 KB
    int t = threadIdx.x;
    int bucket = blockIdx.x;
    if (t < 256) hist[t] = 0;
    __syncthreads();
    int beg = bbase[bucket], end = bbase[bucket + 1];
    int ne = end - beg;
    bool cached = ne <= FCAP;
    if (cached) {
        for (int i = t; i < ne; i += 1024) {
            int p = packed[beg + i];
            ecache[i] = p;
            atomicAdd(&hist[p >> 16], 1);
        }
    } else {
        for (int i = beg + t; i < end; i += 1024)
            atomicAdd(&hist[packed[i] >> 16], 1);
    }
    __syncthreads();
    if (t < 256) scan[t] = hist[t];
    __syncthreads();
    for (int d = 1; d < 256; d <<= 1) {
        int v = 0;
        if (t < 256 && t >= d) v = scan[t - d];
        __syncthreads();
        if (t < 256 && t >= d) scan[t] += v;
        __syncthreads();
    }
    if (t < 256) {
        int excl = beg + scan[t] - hist[t];
        cur[t] = excl;
        int node = bucket * 256 + t;
        if (node < N_NODES) {
            off[node] = excl;
            dinv[node] = rsqrtf((float)(hist[t] + 1));   // +1 self-loop
        }
    }
    __syncthreads();
    if (cached) {
        for (int i = t; i < ne; i += 1024) {
            int p = ecache[i];
            int slot = atomicAdd(&cur[p >> 16], 1);      // LDS atomic
            csr_src[slot] = p & 0xFFFF;
        }
    } else {
        for (int i = beg + t; i < end; i += 1024) {
            int p = packed[i];
            int slot = atomicAdd(&cur[p >> 16], 1);
            csr_src[slot] = p & 0xFFFF;
        }
    }
}

// ---------------- xl' = fp16((x @ W1) * dinv[row]) — 16-row tile, all-LDS inner loop ----------------
// block 256 = 16 rows x 16 col-quads; grid 3125 exact. Output fp16 (8 B per thread).
__global__ __launch_bounds__(256) void k_xw64(const float* __restrict__ x,
                                              const float* __restrict__ W,
                                              const float* __restrict__ dinv,
                                              float2* __restrict__ out /* fp16x4 */) {
    __shared__ float4 sW4[IN_DIM * 16];   // W1: 64 rows x 16 col-quads (16 KB)
    __shared__ float4 sx4[16 * 16];       // x tile: 16 rows x 16 k-quads (4 KB)
    int tid = threadIdx.x;
    const float4* W4 = (const float4*)W;
#pragma unroll
    for (int i = 0; i < 4; ++i) sW4[tid + 256 * i] = W4[tid + 256 * i];
    int rowbase = blockIdx.x * 16;
    sx4[tid] = ((const float4*)(x + (size_t)rowbase * IN_DIM))[tid];  // coalesced
    __syncthreads();
    int r  = tid >> 4;     // row in tile
    int cq = tid & 15;     // col quad
    const float4* sxr = &sx4[r * 16];
    float ax = 0.0f, ay = 0.0f, az = 0.0f, aw = 0.0f;
#pragma unroll
    for (int k4 = 0; k4 < 16; ++k4) {
        float4 xv = sxr[k4];
        float4 w0 = sW4[(k4 * 4 + 0) * 16 + cq];
        float4 w1 = sW4[(k4 * 4 + 1) * 16 + cq];
        float4 w2 = sW4[(k4 * 4 + 2) * 16 + cq];
        float4 w3 = sW4[(k4 * 4 + 3) * 16 + cq];
        ax += xv.x * w0.x + xv.y * w1.x + xv.z * w2.x + xv.w * w3.x;
        ay += xv.x * w0.y + xv.y * w1.y + xv.z * w2.y + xv.w * w3.y;
        az += xv.x * w0.z + xv.y * w1.z + xv.z * w2.z + xv.w * w3.z;
        aw += xv.x * w0.w + xv.y * w1.w + xv.z * w2.w + xv.w * w3.w;
    }
    int row = rowbase + r;
    float dv = dinv[row];
    union { __half2 h[2]; float2 f; } u;
    u.h[0] = __floats2half2_rn(ax * dv, ay * dv);
    u.h[1] = __floats2half2_rn(az * dv, aw * dv);
    out[(size_t)row * 16 + cq] = u.f;
}

// ---------------- fused layer-1 gather + relu + (h@W2)*dinv -> fp16 hl' ----------------
// 16 lanes per node (4 dims each), 4 nodes per wave, 16 nodes per block.
// h stays in registers; W2 applied via LDS + 16-lane butterfly allreduce.
__global__ __launch_bounds__(256) void k_gather64(const float2* __restrict__ xlph,
                                                  const int* __restrict__ csr_src,
                                                  const int* __restrict__ off,
                                                  const float* __restrict__ dinv,
                                                  const float* __restrict__ b1,
                                                  const float* __restrict__ W2,
                                                  __half* __restrict__ hlh /* stride 10 */) {
    __shared__ float sW2[HID_DIM][N_CLS + 1];   // pad 11 -> 2-way bank alias (free)
    int tid = threadIdx.x;
    for (int i = tid; i < HID_DIM * N_CLS; i += 256)
        sW2[i / N_CLS][i - (i / N_CLS) * N_CLS] = W2[i];
    __syncthreads();
    int node = blockIdx.x * 16 + (tid >> 4);   // 50000 = 16*3125 exact
    int d4 = tid & 15;
    int beg = off[node], end = off[node + 1];
    float4 acc = h4_to_f4(xlph[(size_t)node * 16 + d4]);   // self-loop (dinv folded in)
    int j = beg;
    for (; j + 8 <= end; j += 8) {                     // 8-deep per lane chain
        int s0 = csr_src[j],     s1 = csr_src[j + 1];
        int s2 = csr_src[j + 2], s3 = csr_src[j + 3];
        int s4 = csr_src[j + 4], s5 = csr_src[j + 5];
        int s6 = csr_src[j + 6], s7 = csr_src[j + 7];
        float2 r0 = xlph[(size_t)s0 * 16 + d4];
        float2 r1 = xlph[(size_t)s1 * 16 + d4];
        float2 r2 = xlph[(size_t)s2 * 16 + d4];
        float2 r3 = xlph[(size_t)s3 * 16 + d4];
        float2 r4 = xlph[(size_t)s4 * 16 + d4];
        float2 r5 = xlph[(size_t)s5 * 16 + d4];
        float2 r6 = xlph[(size_t)s6 * 16 + d4];
        float2 r7 = xlph[(size_t)s7 * 16 + d4];
        float4 v0 = h4_to_f4(r0), v1 = h4_to_f4(r1);
        float4 v2 = h4_to_f4(r2), v3 = h4_to_f4(r3);
        float4 v4 = h4_to_f4(r4), v5 = h4_to_f4(r5);
        float4 v6 = h4_to_f4(r6), v7 = h4_to_f4(r7);
        acc.x += ((v0.x + v1.x) + (v2.x + v3.x)) + ((v4.x + v5.x) + (v6.x + v7.x));
        acc.y += ((v0.y + v1.y) + (v2.y + v3.y)) + ((v4.y + v5.y) + (v6.y + v7.y));
        acc.z += ((v0.z + v1.z) + (v2.z + v3.z)) + ((v4.z + v5.z) + (v6.z + v7.z));
        acc.w += ((v0.w + v1.w) + (v2.w + v3.w)) + ((v4.w + v5.w) + (v6.w + v7.w));
    }
    for (; j + 4 <= end; j += 4) {
        int s0 = csr_src[j],     s1 = csr_src[j + 1];
        int s2 = csr_src[j + 2], s3 = csr_src[j + 3];
        float4 v0 = h4_to_f4(xlph[(size_t)s0 * 16 + d4]);
        float4 v1 = h4_to_f4(xlph[(size_t)s1 * 16 + d4]);
        float4 v2 = h4_to_f4(xlph[(size_t)s2 * 16 + d4]);
        float4 v3 = h4_to_f4(xlph[(size_t)s3 * 16 + d4]);
        acc.x += (v0.x + v1.x) + (v2.x + v3.x);
        acc.y += (v0.y + v1.y) + (v2.y + v3.y);
        acc.z += (v0.z + v1.z) + (v2.z + v3.z);
        acc.w += (v0.w + v1.w) + (v2.w + v3.w);
    }
    for (; j < end; ++j) {
        float4 v = h4_to_f4(xlph[(size_t)csr_src[j] * 16 + d4]);
        acc.x += v.x; acc.y += v.y; acc.z += v.z; acc.w += v.w;
    }
    float dv = dinv[node];
    float4 bb = ((const float4*)b1)[d4];
    float hx = fmaxf(dv * acc.x + bb.x, 0.0f);   // h[4*d4+0..3] in registers
    float hy = fmaxf(dv * acc.y + bb.y, 0.0f);
    float hz = fmaxf(dv * acc.z + bb.z, 0.0f);
    float hw = fmaxf(dv * acc.w + bb.w, 0.0f);
    float p[N_CLS];
    int k0 = d4 * 4;
#pragma unroll
    for (int c = 0; c < N_CLS; ++c)
        p[c] = hx * sW2[k0 + 0][c] + hy * sW2[k0 + 1][c]
             + hz * sW2[k0 + 2][c] + hw * sW2[k0 + 3][c];
#pragma unroll
    for (int k = 1; k < 16; k <<= 1) {
#pragma unroll
        for (int c = 0; c < N_CLS; ++c) p[c] += __shfl_xor(p[c], k, 64);
    }
    if (d4 < N_CLS) {
        float vsel = p[0];
#pragma unroll
        for (int c = 1; c < N_CLS; ++c) vsel = (d4 == c) ? p[c] : vsel;
        hlh[(size_t)node * N_CLS + d4] = __float2half(vsel * dv);
    }
}

// ---------------- layer-2 gather (fp16 hl) + b2 + log_softmax, 16-lane group per node ----------------
__global__ __launch_bounds__(256) void k_gather10(const __half* __restrict__ hlh,
                                                  const int* __restrict__ csr_src,
                                                  const int* __restrict__ off,
                                                  const float* __restrict__ dinv,
                                                  const float* __restrict__ b2,
                                                  float* __restrict__ out) {
    int t = threadIdx.x;
    int node = blockIdx.x * 16 + (t >> 4);
    int d = t & 15;
    bool act = d < N_CLS;
    int dd = act ? d : 0;
    int beg = off[node], end = off[node + 1];
    float acc = act ? __half2float(hlh[(size_t)node * N_CLS + d]) : 0.0f;
    int j = beg;
    for (; j + 8 <= end; j += 8) {
        int s0 = csr_src[j],     s1 = csr_src[j + 1];
        int s2 = csr_src[j + 2], s3 = csr_src[j + 3];
        int s4 = csr_src[j + 4], s5 = csr_src[j + 5];
        int s6 = csr_src[j + 6], s7 = csr_src[j + 7];
        float v0 = __half2float(hlh[(size_t)s0 * N_CLS + dd]);
        float v1 = __half2float(hlh[(size_t)s1 * N_CLS + dd]);
        float v2 = __half2float(hlh[(size_t)s2 * N_CLS + dd]);
        float v3 = __half2float(hlh[(size_t)s3 * N_CLS + dd]);
        float v4 = __half2float(hlh[(size_t)s4 * N_CLS + dd]);
        float v5 = __half2float(hlh[(size_t)s5 * N_CLS + dd]);
        float v6 = __half2float(hlh[(size_t)s6 * N_CLS + dd]);
        float v7 = __half2float(hlh[(size_t)s7 * N_CLS + dd]);
        if (act) acc += ((v0 + v1) + (v2 + v3)) + ((v4 + v5) + (v6 + v7));
    }
    for (; j + 4 <= end; j += 4) {
        int s0 = csr_src[j],     s1 = csr_src[j + 1];
        int s2 = csr_src[j + 2], s3 = csr_src[j + 3];
        float v0 = __half2float(hlh[(size_t)s0 * N_CLS + dd]);
        float v1 = __half2float(hlh[(size_t)s1 * N_CLS + dd]);
        float v2 = __half2float(hlh[(size_t)s2 * N_CLS + dd]);
        float v3 = __half2float(hlh[(size_t)s3 * N_CLS + dd]);
        if (act) acc += (v0 + v1) + (v2 + v3);
    }
    for (; j < end; ++j) {
        float v = __half2float(hlh[(size_t)csr_src[j] * N_CLS + dd]);
        if (act) acc += v;
    }
    float v = act ? dinv[node] * acc + b2[d] : -INFINITY;
    float m = v;
#pragma unroll
    for (int k = 1; k < 16; k <<= 1) m = fmaxf(m, __shfl_xor(m, k, 64));
    float ex = act ? expf(v - m) : 0.0f;
    float ssum = ex;
#pragma unroll
    for (int k = 1; k < 16; k <<= 1) ssum += __shfl_xor(ssum, k, 64);
    if (act) out[(size_t)node * N_CLS + d] = v - m - logf(ssum);
}

extern "C" void kernel_launch(void* const* d_in, const int* in_sizes, int n_in,
                              void* d_out, int out_size, void* d_ws, size_t ws_size,
                              hipStream_t stream) {
    const float* x  = (const float*)d_in[0];
    const int*   ei = (const int*)d_in[1];
    const float* W1 = (const float*)d_in[2];
    const float* b1 = (const float*)d_in[3];
    const float* W2 = (const float*)d_in[4];
    const float* b2 = (const float*)d_in[5];
    float* out = (float*)d_out;

    const int* src = ei;             // edge_index[0]
    const int* dst = ei + N_EDGES;   // edge_index[1]

    // workspace layout (all segment starts 16B-aligned)
    int*    bhist   = (int*)d_ws;                  // 12544 (pad 12800)
    int*    bbase   = bhist + 12800;               // 197  (pad 256)
    int*    off     = bbase + 256;                 // 50001 (pad 50432)
    int*    packed  = off + 50432;                 // 800000
    int*    csr_src = packed + N_EDGES;            // 800000 (int)
    float*  dinv    = (float*)(csr_src + N_EDGES); // 50000 (pad 50048)
    float2* xlh     = (float2*)(dinv + 50048);     // fp16 xl': 800000 float2 (6.4 MB)
    __half* hlh     = (__half*)(xlh + (size_t)N_NODES * 16);  // fp16 hl': 500000 halfs
                                                   // (separate buffer: written while xlh is read)

    const int B = 256;
    int g_x64 = N_NODES / 16;                     // 3125 exact
    int g_g16 = N_NODES / 16;                     // 3125 exact

    k_chist    <<<PBLK,  1024, 0, stream>>>(dst, bhist);
    k_cscan    <<<1,     1024, 0, stream>>>(bhist, bbase, off);
    k_partition<<<PBLK,  1024, 0, stream>>>(src, dst, bhist, packed);
    k_fine     <<<NBUCK, 1024, 0, stream>>>(packed, bbase, off, dinv, csr_src);
    k_xw64     <<<g_x64,   B, 0, stream>>>(x, W1, dinv, xlh);
    k_gather64 <<<g_g16,   B, 0, stream>>>(xlh, csr_src, off, dinv, b1, W2, hlh);
    k_gather10 <<<g_g16,   B, 0, stream>>>(hlh, csr_src, off, dinv, b2, out);
    (void)in_sizes; (void)n_in; (void)out_size; (void)ws_size;
}

// Round 15
// 143.262 us; speedup vs baseline: 1.1883x; 1.0765x over previous
//
#include <hip/hip_runtime.h>
#include <hip/hip_fp16.h>
#include <math.h>

#define N_NODES  50000
#define N_EDGES  800000
#define IN_DIM   64
#define HID_DIM  64
#define N_CLS    10
#define NBUCK    196      // ceil(N_NODES/256) coarse buckets (dst >> 8)
#define PBLK     256      // partition chunks/blocks (was 64 — now all CUs)
#define PCHUNK   (N_EDGES / PBLK)   // 3125 edges per chunk (exact)
#define FCAP     8192     // k_fine LDS edge cache capacity (32 KB)

// unpack 4 fp16 (carried in a float2) to float4
__device__ __forceinline__ float4 h4_to_f4(float2 raw) {
    union { float2 f; __half2 h[2]; } u;
    u.f = raw;
    float2 lo = __half22float2(u.h[0]);
    float2 hi = __half22float2(u.h[1]);
    return make_float4(lo.x, lo.y, hi.x, hi.y);
}

// ---------------- pass 1a: per-chunk coarse histogram (dst>>8), 256 blocks ----------------
__global__ __launch_bounds__(256) void k_chist(const int* __restrict__ dst,
                                               int* __restrict__ bhist) {
    __shared__ int lh[NBUCK];
    int t = threadIdx.x;
    for (int i = t; i < NBUCK; i += 256) lh[i] = 0;
    __syncthreads();
    int beg = blockIdx.x * PCHUNK, end = beg + PCHUNK;
    for (int e = beg + t; e < end; e += 256)
        atomicAdd(&lh[dst[e] >> 8], 1);          // LDS atomic
    __syncthreads();
    for (int i = t; i < NBUCK; i += 256)
        bhist[i * PBLK + blockIdx.x] = lh[i];    // bin-major
}

// ---------------- pass 1b: per-bin exclusive scan over the 256 chunk counts ----------------
// grid = NBUCK blocks x 256 threads; writes back within-bin offsets + bin totals.
__global__ __launch_bounds__(256) void k_scan2(int* __restrict__ bhist,
                                               int* __restrict__ bintot) {
    __shared__ int s[256];
    int t = threadIdx.x;
    int bin = blockIdx.x;
    int c = bhist[bin * PBLK + t];
    s[t] = c;
    __syncthreads();
    for (int d = 1; d < 256; d <<= 1) {
        int v = (t >= d) ? s[t - d] : 0;
        __syncthreads();
        if (t >= d) s[t] += v;
        __syncthreads();
    }
    bhist[bin * PBLK + t] = s[t] - c;            // exclusive within-bin
    if (t == 255) bintot[bin] = s[255];          // bin total
}

// ---------------- pass 1c: scan 196 bin totals -> bbase (tiny) ----------------
__global__ __launch_bounds__(256) void k_bscan(const int* __restrict__ bintot,
                                               int* __restrict__ bbase,
                                               int* __restrict__ off) {
    __shared__ int s[256];
    int t = threadIdx.x;
    int v = (t < NBUCK) ? bintot[t] : 0;
    s[t] = v;
    __syncthreads();
    for (int d = 1; d < 256; d <<= 1) {
        int u = (t >= d) ? s[t - d] : 0;
        __syncthreads();
        if (t >= d) s[t] += u;
        __syncthreads();
    }
    if (t < NBUCK) bbase[t] = s[t] - v;          // exclusive
    if (t == 0) { bbase[NBUCK] = N_EDGES; off[N_NODES] = N_EDGES; }
}

// ---------------- pass 1d: partition edges into coarse buckets (packed), 256 blocks ----------------
__global__ __launch_bounds__(256) void k_partition(const int* __restrict__ src,
                                                   const int* __restrict__ dst,
                                                   const int* __restrict__ bhist,
                                                   const int* __restrict__ bbase,
                                                   int* __restrict__ packed) {
    __shared__ int cur[NBUCK];
    int t = threadIdx.x;
    for (int i = t; i < NBUCK; i += 256)
        cur[i] = bbase[i] + bhist[i * PBLK + blockIdx.x];
    __syncthreads();
    int beg = blockIdx.x * PCHUNK, end = beg + PCHUNK;
    for (int e = beg + t; e < end; e += 256) {
        int d = dst[e], sv = src[e];
        int slot = atomicAdd(&cur[d >> 8], 1);          // LDS atomic
        packed[slot] = ((d & 255) << 16) | sv;          // run-contiguous per (blk,bin)
    }
}

// ---------------- pass 2: per-bucket fine CSR + off + dinv (LDS edge cache) ----------------
__global__ __launch_bounds__(1024) void k_fine(const int* __restrict__ packed,
                                               const int* __restrict__ bbase,
                                               int* __restrict__ off,
                                               float* __restrict__ dinv,
                                               int* __restrict__ csr_src) {
    __shared__ int hist[256];
    __shared__ int scan[256];
    __shared__ int cur[256];
    __shared__ int ecache[FCAP];            // 32 KB
    int t = threadIdx.x;
    int bucket = blockIdx.x;
    if (t < 256) hist[t] = 0;
    __syncthreads();
    int beg = bbase[bucket], end = bbase[bucket + 1];
    int ne = end - beg;
    bool cached = ne <= FCAP;
    if (cached) {
        for (int i = t; i < ne; i += 1024) {
            int p = packed[beg + i];
            ecache[i] = p;
            atomicAdd(&hist[p >> 16], 1);
        }
    } else {
        for (int i = beg + t; i < end; i += 1024)
            atomicAdd(&hist[packed[i] >> 16], 1);
    }
    __syncthreads();
    if (t < 256) scan[t] = hist[t];
    __syncthreads();
    for (int d = 1; d < 256; d <<= 1) {
        int v = 0;
        if (t < 256 && t >= d) v = scan[t - d];
        __syncthreads();
        if (t < 256 && t >= d) scan[t] += v;
        __syncthreads();
    }
    if (t < 256) {
        int excl = beg + scan[t] - hist[t];
        cur[t] = excl;
        int node = bucket * 256 + t;
        if (node < N_NODES) {
            off[node] = excl;
            dinv[node] = rsqrtf((float)(hist[t] + 1));   // +1 self-loop
        }
    }
    __syncthreads();
    if (cached) {
        for (int i = t; i < ne; i += 1024) {
            int p = ecache[i];
            int slot = atomicAdd(&cur[p >> 16], 1);      // LDS atomic
            csr_src[slot] = p & 0xFFFF;
        }
    } else {
        for (int i = beg + t; i < end; i += 1024) {
            int p = packed[i];
            int slot = atomicAdd(&cur[p >> 16], 1);
            csr_src[slot] = p & 0xFFFF;
        }
    }
}

// ---------------- xl' = fp16((x @ W1) * dinv[row]) — 16-row tile, all-LDS inner loop ----------------
// block 256 = 16 rows x 16 col-quads; grid 3125 exact. Output fp16 (8 B per thread).
__global__ __launch_bounds__(256) void k_xw64(const float* __restrict__ x,
                                              const float* __restrict__ W,
                                              const float* __restrict__ dinv,
                                              float2* __restrict__ out /* fp16x4 */) {
    __shared__ float4 sW4[IN_DIM * 16];   // W1: 64 rows x 16 col-quads (16 KB)
    __shared__ float4 sx4[16 * 16];       // x tile: 16 rows x 16 k-quads (4 KB)
    int tid = threadIdx.x;
    const float4* W4 = (const float4*)W;
#pragma unroll
    for (int i = 0; i < 4; ++i) sW4[tid + 256 * i] = W4[tid + 256 * i];
    int rowbase = blockIdx.x * 16;
    sx4[tid] = ((const float4*)(x + (size_t)rowbase * IN_DIM))[tid];  // coalesced
    __syncthreads();
    int r  = tid >> 4;     // row in tile
    int cq = tid & 15;     // col quad
    const float4* sxr = &sx4[r * 16];
    float ax = 0.0f, ay = 0.0f, az = 0.0f, aw = 0.0f;
#pragma unroll
    for (int k4 = 0; k4 < 16; ++k4) {
        float4 xv = sxr[k4];
        float4 w0 = sW4[(k4 * 4 + 0) * 16 + cq];
        float4 w1 = sW4[(k4 * 4 + 1) * 16 + cq];
        float4 w2 = sW4[(k4 * 4 + 2) * 16 + cq];
        float4 w3 = sW4[(k4 * 4 + 3) * 16 + cq];
        ax += xv.x * w0.x + xv.y * w1.x + xv.z * w2.x + xv.w * w3.x;
        ay += xv.x * w0.y + xv.y * w1.y + xv.z * w2.y + xv.w * w3.y;
        az += xv.x * w0.z + xv.y * w1.z + xv.z * w2.z + xv.w * w3.z;
        aw += xv.x * w0.w + xv.y * w1.w + xv.z * w2.w + xv.w * w3.w;
    }
    int row = rowbase + r;
    float dv = dinv[row];
    union { __half2 h[2]; float2 f; } u;
    u.h[0] = __floats2half2_rn(ax * dv, ay * dv);
    u.h[1] = __floats2half2_rn(az * dv, aw * dv);
    out[(size_t)row * 16 + cq] = u.f;
}

// ---------------- fused layer-1 gather + relu + (h@W2)*dinv -> fp16 hl' ----------------
// 16 lanes per node (4 dims each), 4 nodes per wave, 16 nodes per block.
// h stays in registers; W2 applied via LDS + 16-lane butterfly allreduce.
__global__ __launch_bounds__(256) void k_gather64(const float2* __restrict__ xlph,
                                                  const int* __restrict__ csr_src,
                                                  const int* __restrict__ off,
                                                  const float* __restrict__ dinv,
                                                  const float* __restrict__ b1,
                                                  const float* __restrict__ W2,
                                                  __half* __restrict__ hlh /* stride 10 */) {
    __shared__ float sW2[HID_DIM][N_CLS + 1];   // pad 11 -> 2-way bank alias (free)
    int tid = threadIdx.x;
    for (int i = tid; i < HID_DIM * N_CLS; i += 256)
        sW2[i / N_CLS][i - (i / N_CLS) * N_CLS] = W2[i];
    __syncthreads();
    int node = blockIdx.x * 16 + (tid >> 4);   // 50000 = 16*3125 exact
    int d4 = tid & 15;
    int beg = off[node], end = off[node + 1];
    float4 acc = h4_to_f4(xlph[(size_t)node * 16 + d4]);   // self-loop (dinv folded in)
    int j = beg;
    for (; j + 8 <= end; j += 8) {                     // 8-deep per lane chain
        int s0 = csr_src[j],     s1 = csr_src[j + 1];
        int s2 = csr_src[j + 2], s3 = csr_src[j + 3];
        int s4 = csr_src[j + 4], s5 = csr_src[j + 5];
        int s6 = csr_src[j + 6], s7 = csr_src[j + 7];
        float2 r0 = xlph[(size_t)s0 * 16 + d4];
        float2 r1 = xlph[(size_t)s1 * 16 + d4];
        float2 r2 = xlph[(size_t)s2 * 16 + d4];
        float2 r3 = xlph[(size_t)s3 * 16 + d4];
        float2 r4 = xlph[(size_t)s4 * 16 + d4];
        float2 r5 = xlph[(size_t)s5 * 16 + d4];
        float2 r6 = xlph[(size_t)s6 * 16 + d4];
        float2 r7 = xlph[(size_t)s7 * 16 + d4];
        float4 v0 = h4_to_f4(r0), v1 = h4_to_f4(r1);
        float4 v2 = h4_to_f4(r2), v3 = h4_to_f4(r3);
        float4 v4 = h4_to_f4(r4), v5 = h4_to_f4(r5);
        float4 v6 = h4_to_f4(r6), v7 = h4_to_f4(r7);
        acc.x += ((v0.x + v1.x) + (v2.x + v3.x)) + ((v4.x + v5.x) + (v6.x + v7.x));
        acc.y += ((v0.y + v1.y) + (v2.y + v3.y)) + ((v4.y + v5.y) + (v6.y + v7.y));
        acc.z += ((v0.z + v1.z) + (v2.z + v3.z)) + ((v4.z + v5.z) + (v6.z + v7.z));
        acc.w += ((v0.w + v1.w) + (v2.w + v3.w)) + ((v4.w + v5.w) + (v6.w + v7.w));
    }
    for (; j + 4 <= end; j += 4) {
        int s0 = csr_src[j],     s1 = csr_src[j + 1];
        int s2 = csr_src[j + 2], s3 = csr_src[j + 3];
        float4 v0 = h4_to_f4(xlph[(size_t)s0 * 16 + d4]);
        float4 v1 = h4_to_f4(xlph[(size_t)s1 * 16 + d4]);
        float4 v2 = h4_to_f4(xlph[(size_t)s2 * 16 + d4]);
        float4 v3 = h4_to_f4(xlph[(size_t)s3 * 16 + d4]);
        acc.x += (v0.x + v1.x) + (v2.x + v3.x);
        acc.y += (v0.y + v1.y) + (v2.y + v3.y);
        acc.z += (v0.z + v1.z) + (v2.z + v3.z);
        acc.w += (v0.w + v1.w) + (v2.w + v3.w);
    }
    for (; j < end; ++j) {
        float4 v = h4_to_f4(xlph[(size_t)csr_src[j] * 16 + d4]);
        acc.x += v.x; acc.y += v.y; acc.z += v.z; acc.w += v.w;
    }
    float dv = dinv[node];
    float4 bb = ((const float4*)b1)[d4];
    float hx = fmaxf(dv * acc.x + bb.x, 0.0f);   // h[4*d4+0..3] in registers
    float hy = fmaxf(dv * acc.y + bb.y, 0.0f);
    float hz = fmaxf(dv * acc.z + bb.z, 0.0f);
    float hw = fmaxf(dv * acc.w + bb.w, 0.0f);
    float p[N_CLS];
    int k0 = d4 * 4;
#pragma unroll
    for (int c = 0; c < N_CLS; ++c)
        p[c] = hx * sW2[k0 + 0][c] + hy * sW2[k0 + 1][c]
             + hz * sW2[k0 + 2][c] + hw * sW2[k0 + 3][c];
#pragma unroll
    for (int k = 1; k < 16; k <<= 1) {
#pragma unroll
        for (int c = 0; c < N_CLS; ++c) p[c] += __shfl_xor(p[c], k, 64);
    }
    if (d4 < N_CLS) {
        float vsel = p[0];
#pragma unroll
        for (int c = 1; c < N_CLS; ++c) vsel = (d4 == c) ? p[c] : vsel;
        hlh[(size_t)node * N_CLS + d4] = __float2half(vsel * dv);
    }
}

// ---------------- layer-2 gather (fp16 hl) + b2 + log_softmax, 16-lane group per node ----------------
__global__ __launch_bounds__(256) void k_gather10(const __half* __restrict__ hlh,
                                                  const int* __restrict__ csr_src,
                                                  const int* __restrict__ off,
                                                  const float* __restrict__ dinv,
                                                  const float* __restrict__ b2,
                                                  float* __restrict__ out) {
    int t = threadIdx.x;
    int node = blockIdx.x * 16 + (t >> 4);
    int d = t & 15;
    bool act = d < N_CLS;
    int dd = act ? d : 0;
    int beg = off[node], end = off[node + 1];
    float acc = act ? __half2float(hlh[(size_t)node * N_CLS + d]) : 0.0f;
    int j = beg;
    for (; j + 8 <= end; j += 8) {
        int s0 = csr_src[j],     s1 = csr_src[j + 1];
        int s2 = csr_src[j + 2], s3 = csr_src[j + 3];
        int s4 = csr_src[j + 4], s5 = csr_src[j + 5];
        int s6 = csr_src[j + 6], s7 = csr_src[j + 7];
        float v0 = __half2float(hlh[(size_t)s0 * N_CLS + dd]);
        float v1 = __half2float(hlh[(size_t)s1 * N_CLS + dd]);
        float v2 = __half2float(hlh[(size_t)s2 * N_CLS + dd]);
        float v3 = __half2float(hlh[(size_t)s3 * N_CLS + dd]);
        float v4 = __half2float(hlh[(size_t)s4 * N_CLS + dd]);
        float v5 = __half2float(hlh[(size_t)s5 * N_CLS + dd]);
        float v6 = __half2float(hlh[(size_t)s6 * N_CLS + dd]);
        float v7 = __half2float(hlh[(size_t)s7 * N_CLS + dd]);
        if (act) acc += ((v0 + v1) + (v2 + v3)) + ((v4 + v5) + (v6 + v7));
    }
    for (; j + 4 <= end; j += 4) {
        int s0 = csr_src[j],     s1 = csr_src[j + 1];
        int s2 = csr_src[j + 2], s3 = csr_src[j + 3];
        float v0 = __half2float(hlh[(size_t)s0 * N_CLS + dd]);
        float v1 = __half2float(hlh[(size_t)s1 * N_CLS + dd]);
        float v2 = __half2float(hlh[(size_t)s2 * N_CLS + dd]);
        float v3 = __half2float(hlh[(size_t)s3 * N_CLS + dd]);
        if (act) acc += (v0 + v1) + (v2 + v3);
    }
    for (; j < end; ++j) {
        float v = __half2float(hlh[(size_t)csr_src[j] * N_CLS + dd]);
        if (act) acc += v;
    }
    float v = act ? dinv[node] * acc + b2[d] : -INFINITY;
    float m = v;
#pragma unroll
    for (int k = 1; k < 16; k <<= 1) m = fmaxf(m, __shfl_xor(m, k, 64));
    float ex = act ? expf(v - m) : 0.0f;
    float ssum = ex;
#pragma unroll
    for (int k = 1; k < 16; k <<= 1) ssum += __shfl_xor(ssum, k, 64);
    if (act) out[(size_t)node * N_CLS + d] = v - m - logf(ssum);
}

extern "C" void kernel_launch(void* const* d_in, const int* in_sizes, int n_in,
                              void* d_out, int out_size, void* d_ws, size_t ws_size,
                              hipStream_t stream) {
    const float* x  = (const float*)d_in[0];
    const int*   ei = (const int*)d_in[1];
    const float* W1 = (const float*)d_in[2];
    const float* b1 = (const float*)d_in[3];
    const float* W2 = (const float*)d_in[4];
    const float* b2 = (const float*)d_in[5];
    float* out = (float*)d_out;

    const int* src = ei;             // edge_index[0]
    const int* dst = ei + N_EDGES;   // edge_index[1]

    // workspace layout (all segment starts 16B-aligned)
    int*    bhist   = (int*)d_ws;                  // 196*256 = 50176 (pad 50432)
    int*    bintot  = bhist + 50432;               // 196 (pad 256)
    int*    bbase   = bintot + 256;                // 197 (pad 256)
    int*    off     = bbase + 256;                 // 50001 (pad 50432)
    int*    packed  = off + 50432;                 // 800000
    int*    csr_src = packed + N_EDGES;            // 800000 (int)
    float*  dinv    = (float*)(csr_src + N_EDGES); // 50000 (pad 50048)
    float2* xlh     = (float2*)(dinv + 50048);     // fp16 xl': 800000 float2 (6.4 MB)
    __half* hlh     = (__half*)(xlh + (size_t)N_NODES * 16);  // fp16 hl': 500000 halfs

    const int B = 256;
    int g_x64 = N_NODES / 16;                     // 3125 exact
    int g_g16 = N_NODES / 16;                     // 3125 exact

    k_chist    <<<PBLK,  B, 0, stream>>>(dst, bhist);
    k_scan2    <<<NBUCK, B, 0, stream>>>(bhist, bintot);
    k_bscan    <<<1,     B, 0, stream>>>(bintot, bbase, off);
    k_partition<<<PBLK,  B, 0, stream>>>(src, dst, bhist, bbase, packed);
    k_fine     <<<NBUCK, 1024, 0, stream>>>(packed, bbase, off, dinv, csr_src);
    k_xw64     <<<g_x64,   B, 0, stream>>>(x, W1, dinv, xlh);
    k_gather64 <<<g_g16,   B, 0, stream>>>(xlh, csr_src, off, dinv, b1, W2, hlh);
    k_gather10 <<<g_g16,   B, 0, stream>>>(hlh, csr_src, off, dinv, b2, out);
    (void)in_sizes; (void)n_in; (void)out_size; (void)ws_size;
}

// Round 16
// 139.828 us; speedup vs baseline: 1.2175x; 1.0246x over previous
//
#include <hip/hip_runtime.h>
#include <hip/hip_fp16.h>
#include <math.h>

#define N_NODES  50000
#define N_EDGES  800000
#define IN_DIM   64
#define HID_DIM  64
#define N_CLS    10
#define NBUCK    196      // ceil(N_NODES/256) coarse buckets (dst >> 8)
#define PBLK     256      // partition chunks/blocks
#define PCHUNK   (N_EDGES / PBLK)   // 3125 edges per chunk (exact)
#define FCAP     8192     // k_fine LDS edge cache capacity (32 KB)
#define CSTRIDE  8192     // fixed csr slots per bucket (max bucket ~5.3k incl pads)
#define ZROW     50000    // zero-row index for pad gathers

// unpack 4 fp16 (carried in a float2) to float4
__device__ __forceinline__ float4 h4_to_f4(float2 raw) {
    union { float2 f; __half2 h[2]; } u;
    u.f = raw;
    float2 lo = __half22float2(u.h[0]);
    float2 hi = __half22float2(u.h[1]);
    return make_float4(lo.x, lo.y, hi.x, hi.y);
}

// ---------------- pass 1a: per-chunk coarse histogram (dst>>8), 256 blocks ----------------
__global__ __launch_bounds__(256) void k_chist(const int* __restrict__ dst,
                                               int* __restrict__ bhist) {
    __shared__ int lh[NBUCK];
    int t = threadIdx.x;
    for (int i = t; i < NBUCK; i += 256) lh[i] = 0;
    __syncthreads();
    int beg = blockIdx.x * PCHUNK, end = beg + PCHUNK;
    for (int e = beg + t; e < end; e += 256)
        atomicAdd(&lh[dst[e] >> 8], 1);          // LDS atomic
    __syncthreads();
    for (int i = t; i < NBUCK; i += 256)
        bhist[i * PBLK + blockIdx.x] = lh[i];    // bin-major
}

// ---------------- pass 1b: per-bin exclusive scan over the 256 chunk counts ----------------
__global__ __launch_bounds__(256) void k_scan2(int* __restrict__ bhist,
                                               int* __restrict__ bintot) {
    __shared__ int s[256];
    int t = threadIdx.x;
    int bin = blockIdx.x;
    int c = bhist[bin * PBLK + t];
    s[t] = c;
    __syncthreads();
    for (int d = 1; d < 256; d <<= 1) {
        int v = (t >= d) ? s[t - d] : 0;
        __syncthreads();
        if (t >= d) s[t] += v;
        __syncthreads();
    }
    bhist[bin * PBLK + t] = s[t] - c;            // exclusive within-bin
    if (t == 255) bintot[bin] = s[255];          // bin total
}

// ---------------- pass 1c: scan 196 bin totals -> bbase; zero the ZROW pads ----------------
__global__ __launch_bounds__(256) void k_bscan(const int* __restrict__ bintot,
                                               int* __restrict__ bbase,
                                               float2* __restrict__ xlh,
                                               __half* __restrict__ hlh) {
    __shared__ int s[256];
    int t = threadIdx.x;
    int v = (t < NBUCK) ? bintot[t] : 0;
    s[t] = v;
    __syncthreads();
    for (int d = 1; d < 256; d <<= 1) {
        int u = (t >= d) ? s[t - d] : 0;
        __syncthreads();
        if (t >= d) s[t] += u;
        __syncthreads();
    }
    if (t < NBUCK) bbase[t] = s[t] - v;          // exclusive
    if (t == 0) bbase[NBUCK] = N_EDGES;
    // zero rows consumed by pad gathers
    if (t < 16) xlh[(size_t)ZROW * 16 + t] = make_float2(0.f, 0.f);
    if (t >= 16 && t < 26) hlh[(size_t)ZROW * N_CLS + (t - 16)] = __float2half(0.f);
}

// ---------------- pass 1d: partition edges into coarse buckets (packed), 256 blocks ----------------
__global__ __launch_bounds__(256) void k_partition(const int* __restrict__ src,
                                                   const int* __restrict__ dst,
                                                   const int* __restrict__ bhist,
                                                   const int* __restrict__ bbase,
                                                   int* __restrict__ packed) {
    __shared__ int cur[NBUCK];
    int t = threadIdx.x;
    for (int i = t; i < NBUCK; i += 256)
        cur[i] = bbase[i] + bhist[i * PBLK + blockIdx.x];
    __syncthreads();
    int beg = blockIdx.x * PCHUNK, end = beg + PCHUNK;
    for (int e = beg + t; e < end; e += 256) {
        int d = dst[e], sv = src[e];
        int slot = atomicAdd(&cur[d >> 8], 1);          // LDS atomic
        packed[slot] = ((d & 255) << 16) | sv;          // run-contiguous per (blk,bin)
    }
}

// ---------------- pass 2: per-bucket fine CSR (padded to x4) + off/nend + dinv ----------------
// csr region for bucket b is fixed: [b*CSTRIDE, (b+1)*CSTRIDE). Pad slots -> ZROW.
__global__ __launch_bounds__(1024) void k_fine(const int* __restrict__ packed,
                                               const int* __restrict__ bbase,
                                               int* __restrict__ off,
                                               int* __restrict__ nend,
                                               float* __restrict__ dinv,
                                               int* __restrict__ csr) {
    __shared__ int hist[256];
    __shared__ int scan[256];
    __shared__ int cur[256];
    __shared__ int ecache[FCAP];            // 32 KB
    int t = threadIdx.x;
    int bucket = blockIdx.x;
    if (t < 256) hist[t] = 0;
    __syncthreads();
    int beg = bbase[bucket], end = bbase[bucket + 1];
    int ne = end - beg;
    bool cached = ne <= FCAP;
    if (cached) {
        for (int i = t; i < ne; i += 1024) {
            int p = packed[beg + i];
            ecache[i] = p;
            atomicAdd(&hist[p >> 16], 1);
        }
    } else {
        for (int i = beg + t; i < end; i += 1024)
            atomicAdd(&hist[packed[i] >> 16], 1);
    }
    __syncthreads();
    int padded = (t < 256) ? ((hist[t] + 3) & ~3) : 0;
    if (t < 256) scan[t] = padded;
    __syncthreads();
    for (int d = 1; d < 256; d <<= 1) {
        int v = 0;
        if (t < 256 && t >= d) v = scan[t - d];
        __syncthreads();
        if (t < 256 && t >= d) scan[t] += v;
        __syncthreads();
    }
    int base = bucket * CSTRIDE;
    if (t < 256) {
        int o = base + scan[t] - padded;             // exclusive padded prefix
        cur[t] = o;
        int node = bucket * 256 + t;
        if (node < N_NODES) {
            off[node]  = o;
            nend[node] = o + padded;
            dinv[node] = rsqrtf((float)(hist[t] + 1));   // +1 self-loop
        }
    }
    __syncthreads();
    if (cached) {
        for (int i = t; i < ne; i += 1024) {
            int p = ecache[i];
            int slot = atomicAdd(&cur[p >> 16], 1);      // LDS atomic
            csr[slot] = p & 0xFFFF;
        }
    } else {
        for (int i = beg + t; i < end; i += 1024) {
            int p = packed[i];
            int slot = atomicAdd(&cur[p >> 16], 1);
            csr[slot] = p & 0xFFFF;
        }
    }
    __syncthreads();
    if (t < 256) {
        int node = bucket * 256 + t;
        if (node < N_NODES) {
            int e2 = nend[node];
            for (int i = cur[t]; i < e2; ++i) csr[i] = ZROW;   // <=3 pad fills
        }
    }
}

// ---------------- xl' = fp16((x @ W1) * dinv[row]) — 16-row tile, all-LDS inner loop ----------------
__global__ __launch_bounds__(256) void k_xw64(const float* __restrict__ x,
                                              const float* __restrict__ W,
                                              const float* __restrict__ dinv,
                                              float2* __restrict__ out /* fp16x4 */) {
    __shared__ float4 sW4[IN_DIM * 16];   // W1: 64 rows x 16 col-quads (16 KB)
    __shared__ float4 sx4[16 * 16];       // x tile: 16 rows x 16 k-quads (4 KB)
    int tid = threadIdx.x;
    const float4* W4 = (const float4*)W;
#pragma unroll
    for (int i = 0; i < 4; ++i) sW4[tid + 256 * i] = W4[tid + 256 * i];
    int rowbase = blockIdx.x * 16;
    sx4[tid] = ((const float4*)(x + (size_t)rowbase * IN_DIM))[tid];  // coalesced
    __syncthreads();
    int r  = tid >> 4;     // row in tile
    int cq = tid & 15;     // col quad
    const float4* sxr = &sx4[r * 16];
    float ax = 0.0f, ay = 0.0f, az = 0.0f, aw = 0.0f;
#pragma unroll
    for (int k4 = 0; k4 < 16; ++k4) {
        float4 xv = sxr[k4];
        float4 w0 = sW4[(k4 * 4 + 0) * 16 + cq];
        float4 w1 = sW4[(k4 * 4 + 1) * 16 + cq];
        float4 w2 = sW4[(k4 * 4 + 2) * 16 + cq];
        float4 w3 = sW4[(k4 * 4 + 3) * 16 + cq];
        ax += xv.x * w0.x + xv.y * w1.x + xv.z * w2.x + xv.w * w3.x;
        ay += xv.x * w0.y + xv.y * w1.y + xv.z * w2.y + xv.w * w3.y;
        az += xv.x * w0.z + xv.y * w1.z + xv.z * w2.z + xv.w * w3.z;
        aw += xv.x * w0.w + xv.y * w1.w + xv.z * w2.w + xv.w * w3.w;
    }
    int row = rowbase + r;
    float dv = dinv[row];
    union { __half2 h[2]; float2 f; } u;
    u.h[0] = __floats2half2_rn(ax * dv, ay * dv);
    u.h[1] = __floats2half2_rn(az * dv, aw * dv);
    out[(size_t)row * 16 + cq] = u.f;
}

// ---------------- fused layer-1 gather + relu + (h@W2)*dinv -> fp16 hl' ----------------
// 16 lanes per node (4 dims each); csr indices loaded as aligned int4; loops branchless.
__global__ __launch_bounds__(256) void k_gather64(const float2* __restrict__ xlph,
                                                  const int* __restrict__ csr,
                                                  const int* __restrict__ off,
                                                  const int* __restrict__ nend,
                                                  const float* __restrict__ dinv,
                                                  const float* __restrict__ b1,
                                                  const float* __restrict__ W2,
                                                  __half* __restrict__ hlh /* stride 10 */) {
    __shared__ float sW2[HID_DIM][N_CLS + 1];   // pad 11 -> 2-way bank alias (free)
    int tid = threadIdx.x;
    for (int i = tid; i < HID_DIM * N_CLS; i += 256)
        sW2[i / N_CLS][i - (i / N_CLS) * N_CLS] = W2[i];
    __syncthreads();
    int node = blockIdx.x * 16 + (tid >> 4);   // 50000 = 16*3125 exact
    int d4 = tid & 15;
    int beg = off[node], end = nend[node];
    float4 acc = h4_to_f4(xlph[(size_t)node * 16 + d4]);   // self-loop (dinv folded in)
    int j = beg;
    for (; j + 8 <= end; j += 8) {                     // 2 int4 index loads + 8 gathers
        int4 c0 = *(const int4*)(csr + j);
        int4 c1 = *(const int4*)(csr + j + 4);
        float2 r0 = xlph[(size_t)c0.x * 16 + d4];
        float2 r1 = xlph[(size_t)c0.y * 16 + d4];
        float2 r2 = xlph[(size_t)c0.z * 16 + d4];
        float2 r3 = xlph[(size_t)c0.w * 16 + d4];
        float2 r4 = xlph[(size_t)c1.x * 16 + d4];
        float2 r5 = xlph[(size_t)c1.y * 16 + d4];
        float2 r6 = xlph[(size_t)c1.z * 16 + d4];
        float2 r7 = xlph[(size_t)c1.w * 16 + d4];
        float4 v0 = h4_to_f4(r0), v1 = h4_to_f4(r1);
        float4 v2 = h4_to_f4(r2), v3 = h4_to_f4(r3);
        float4 v4 = h4_to_f4(r4), v5 = h4_to_f4(r5);
        float4 v6 = h4_to_f4(r6), v7 = h4_to_f4(r7);
        acc.x += ((v0.x + v1.x) + (v2.x + v3.x)) + ((v4.x + v5.x) + (v6.x + v7.x));
        acc.y += ((v0.y + v1.y) + (v2.y + v3.y)) + ((v4.y + v5.y) + (v6.y + v7.y));
        acc.z += ((v0.z + v1.z) + (v2.z + v3.z)) + ((v4.z + v5.z) + (v6.z + v7.z));
        acc.w += ((v0.w + v1.w) + (v2.w + v3.w)) + ((v4.w + v5.w) + (v6.w + v7.w));
    }
    if (j < end) {                                     // exactly one padded 4-block
        int4 c0 = *(const int4*)(csr + j);
        float4 v0 = h4_to_f4(xlph[(size_t)c0.x * 16 + d4]);
        float4 v1 = h4_to_f4(xlph[(size_t)c0.y * 16 + d4]);
        float4 v2 = h4_to_f4(xlph[(size_t)c0.z * 16 + d4]);
        float4 v3 = h4_to_f4(xlph[(size_t)c0.w * 16 + d4]);
        acc.x += (v0.x + v1.x) + (v2.x + v3.x);
        acc.y += (v0.y + v1.y) + (v2.y + v3.y);
        acc.z += (v0.z + v1.z) + (v2.z + v3.z);
        acc.w += (v0.w + v1.w) + (v2.w + v3.w);
    }
    float dv = dinv[node];
    float4 bb = ((const float4*)b1)[d4];
    float hx = fmaxf(dv * acc.x + bb.x, 0.0f);   // h[4*d4+0..3] in registers
    float hy = fmaxf(dv * acc.y + bb.y, 0.0f);
    float hz = fmaxf(dv * acc.z + bb.z, 0.0f);
    float hw = fmaxf(dv * acc.w + bb.w, 0.0f);
    float p[N_CLS];
    int k0 = d4 * 4;
#pragma unroll
    for (int c = 0; c < N_CLS; ++c)
        p[c] = hx * sW2[k0 + 0][c] + hy * sW2[k0 + 1][c]
             + hz * sW2[k0 + 2][c] + hw * sW2[k0 + 3][c];
#pragma unroll
    for (int k = 1; k < 16; k <<= 1) {
#pragma unroll
        for (int c = 0; c < N_CLS; ++c) p[c] += __shfl_xor(p[c], k, 64);
    }
    if (d4 < N_CLS) {
        float vsel = p[0];
#pragma unroll
        for (int c = 1; c < N_CLS; ++c) vsel = (d4 == c) ? p[c] : vsel;
        hlh[(size_t)node * N_CLS + d4] = __float2half(vsel * dv);
    }
}

// ---------------- layer-2 gather (fp16 hl) + b2 + log_softmax, 16-lane group per node ----------------
__global__ __launch_bounds__(256) void k_gather10(const __half* __restrict__ hlh,
                                                  const int* __restrict__ csr,
                                                  const int* __restrict__ off,
                                                  const int* __restrict__ nend,
                                                  const float* __restrict__ dinv,
                                                  const float* __restrict__ b2,
                                                  float* __restrict__ out) {
    int t = threadIdx.x;
    int node = blockIdx.x * 16 + (t >> 4);
    int d = t & 15;
    bool act = d < N_CLS;
    int dd = act ? d : 0;
    int beg = off[node], end = nend[node];
    float acc = act ? __half2float(hlh[(size_t)node * N_CLS + d]) : 0.0f;
    int j = beg;
    for (; j + 8 <= end; j += 8) {
        int4 c0 = *(const int4*)(csr + j);
        int4 c1 = *(const int4*)(csr + j + 4);
        float v0 = __half2float(hlh[(size_t)c0.x * N_CLS + dd]);
        float v1 = __half2float(hlh[(size_t)c0.y * N_CLS + dd]);
        float v2 = __half2float(hlh[(size_t)c0.z * N_CLS + dd]);
        float v3 = __half2float(hlh[(size_t)c0.w * N_CLS + dd]);
        float v4 = __half2float(hlh[(size_t)c1.x * N_CLS + dd]);
        float v5 = __half2float(hlh[(size_t)c1.y * N_CLS + dd]);
        float v6 = __half2float(hlh[(size_t)c1.z * N_CLS + dd]);
        float v7 = __half2float(hlh[(size_t)c1.w * N_CLS + dd]);
        if (act) acc += ((v0 + v1) + (v2 + v3)) + ((v4 + v5) + (v6 + v7));
    }
    if (j < end) {
        int4 c0 = *(const int4*)(csr + j);
        float v0 = __half2float(hlh[(size_t)c0.x * N_CLS + dd]);
        float v1 = __half2float(hlh[(size_t)c0.y * N_CLS + dd]);
        float v2 = __half2float(hlh[(size_t)c0.z * N_CLS + dd]);
        float v3 = __half2float(hlh[(size_t)c0.w * N_CLS + dd]);
        if (act) acc += (v0 + v1) + (v2 + v3);
    }
    float v = act ? dinv[node] * acc + b2[d] : -INFINITY;
    float m = v;
#pragma unroll
    for (int k = 1; k < 16; k <<= 1) m = fmaxf(m, __shfl_xor(m, k, 64));
    float ex = act ? expf(v - m) : 0.0f;
    float ssum = ex;
#pragma unroll
    for (int k = 1; k < 16; k <<= 1) ssum += __shfl_xor(ssum, k, 64);
    if (act) out[(size_t)node * N_CLS + d] = v - m - logf(ssum);
}

extern "C" void kernel_launch(void* const* d_in, const int* in_sizes, int n_in,
                              void* d_out, int out_size, void* d_ws, size_t ws_size,
                              hipStream_t stream) {
    const float* x  = (const float*)d_in[0];
    const int*   ei = (const int*)d_in[1];
    const float* W1 = (const float*)d_in[2];
    const float* b1 = (const float*)d_in[3];
    const float* W2 = (const float*)d_in[4];
    const float* b2 = (const float*)d_in[5];
    float* out = (float*)d_out;

    const int* src = ei;             // edge_index[0]
    const int* dst = ei + N_EDGES;   // edge_index[1]

    // workspace layout (all segment starts 16B-aligned)
    int*    bhist  = (int*)d_ws;                   // 196*256 = 50176 (pad 50432)
    int*    bintot = bhist + 50432;                // 196 (pad 256)
    int*    bbase  = bintot + 256;                 // 197 (pad 256)
    int*    off    = bbase + 256;                  // 50000 (pad 50048)
    int*    nend   = off + 50048;                  // 50000 (pad 50048)
    int*    packed = nend + 50048;                 // 800000
    int*    csr    = packed + N_EDGES;             // 196*8192 = 1605632 (6.4 MB)
    float*  dinv   = (float*)(csr + NBUCK * CSTRIDE); // 50000 (pad 50048)
    float2* xlh    = (float2*)(dinv + 50048);      // fp16 xl': 50001 rows x 16 float2
    __half* hlh    = (__half*)(xlh + (size_t)(N_NODES + 1) * 16);  // fp16 hl': 50001 x 10

    const int B = 256;
    int g_x64 = N_NODES / 16;                     // 3125 exact
    int g_g16 = N_NODES / 16;                     // 3125 exact

    k_chist    <<<PBLK,  B, 0, stream>>>(dst, bhist);
    k_scan2    <<<NBUCK, B, 0, stream>>>(bhist, bintot);
    k_bscan    <<<1,     B, 0, stream>>>(bintot, bbase, xlh, hlh);
    k_partition<<<PBLK,  B, 0, stream>>>(src, dst, bhist, bbase, packed);
    k_fine     <<<NBUCK, 1024, 0, stream>>>(packed, bbase, off, nend, dinv, csr);
    k_xw64     <<<g_x64,   B, 0, stream>>>(x, W1, dinv, xlh);
    k_gather64 <<<g_g16,   B, 0, stream>>>(xlh, csr, off, nend, dinv, b1, W2, hlh);
    k_gather10 <<<g_g16,   B, 0, stream>>>(hlh, csr, off, nend, dinv, b2, out);
    (void)in_sizes; (void)n_in; (void)out_size; (void)ws_size;
}